// Round 8
// baseline (448.789 us; speedup 1.0000x reference)
//
#include <hip/hip_runtime.h>
#include <hip/hip_bf16.h>
#include <stdint.h>

using u16 = unsigned short;
typedef float floatx4 __attribute__((ext_vector_type(4)));
typedef __bf16 bfv8 __attribute__((ext_vector_type(8)));

#define AS1 __attribute__((address_space(1)))
#define AS3 __attribute__((address_space(3)))

__device__ __forceinline__ u16 f2bf_bits(float f) {
    __hip_bfloat16 h = __float2bfloat16(f);
    u16 u;
    __builtin_memcpy(&u, &h, 2);
    return u;
}
__device__ __forceinline__ float bf_bits2f(u16 u) {
    __hip_bfloat16 h;
    __builtin_memcpy(&h, &u, 2);
    return __bfloat162float(h);
}
__device__ __forceinline__ void gload_lds16(const void* g, void* l) {
    __builtin_amdgcn_global_load_lds((AS1 void*)(uintptr_t)g, (AS3 void*)l, 16, 0, 0);
}

// ---- BK=64 tile staging (dbuf), XOR-swizzled chunks ----
__device__ __forceinline__ void stage64(const u16* __restrict__ Abase, long lda, const long* arow,
                                        const u16* __restrict__ Bb, long ldb, int k0, int tid,
                                        u16* Ad, u16* Bd) {
    #pragma unroll
    for (int j = 0; j < 4; ++j) {
        const int q   = j * 256 + tid;
        const int row = q >> 3;
        const int cg  = (q & 7) ^ (row & 7);
        gload_lds16(Abase + arow[j] * lda + k0 + cg * 8, Ad + q * 8);
        gload_lds16(Bb + (long)row * ldb + k0 + cg * 8, Bd + q * 8);
    }
}
// stage a single 128x64 chunk (contiguous rows)
__device__ __forceinline__ void stage_one(const u16* __restrict__ base, long ld, int tid, u16* dst) {
    #pragma unroll
    for (int j = 0; j < 4; ++j) {
        const int q   = j * 256 + tid;
        const int row = q >> 3;
        const int cg  = (q & 7) ^ (row & 7);
        gload_lds16(base + (long)row * ld + cg * 8, dst + q * 8);
    }
}
__device__ __forceinline__ void compute64(const u16* Ab, const u16* Bb, int wy, int wx,
                                          int quad, int mrow, floatx4 acc[4][4]) {
    #pragma unroll
    for (int kk = 0; kk < 2; ++kk) {
        bfv8 af[4], bf[4];
        #pragma unroll
        for (int mi = 0; mi < 4; mi++) {
            const int r = wy * 64 + mi * 16 + mrow;
            const int slot = (kk * 4 + quad) ^ (r & 7);
            af[mi] = *(const bfv8*)&Ab[r * 64 + slot * 8];
        }
        #pragma unroll
        for (int ni = 0; ni < 4; ni++) {
            const int r = wx * 64 + ni * 16 + mrow;
            const int slot = (kk * 4 + quad) ^ (r & 7);
            bf[ni] = *(const bfv8*)&Bb[r * 64 + slot * 8];
        }
        #pragma unroll
        for (int mi = 0; mi < 4; mi++)
            #pragma unroll
            for (int ni = 0; ni < 4; ni++)
                acc[mi][ni] = __builtin_amdgcn_mfma_f32_16x16x32_bf16(af[mi], bf[ni], acc[mi][ni], 0, 0, 0);
    }
}
// A from LDS (K-tile rows=keys), B from registers (Q fragments)
__device__ __forceinline__ void computeQK(const u16* Kb, const bfv8 qf[2][4], int wy,
                                          int quad, int mrow, floatx4 acc[4][4]) {
    #pragma unroll
    for (int kk = 0; kk < 2; ++kk) {
        bfv8 af[4];
        #pragma unroll
        for (int mi = 0; mi < 4; mi++) {
            const int r = wy * 64 + mi * 16 + mrow;
            const int slot = (kk * 4 + quad) ^ (r & 7);
            af[mi] = *(const bfv8*)&Kb[r * 64 + slot * 8];
        }
        #pragma unroll
        for (int mi = 0; mi < 4; mi++)
            #pragma unroll
            for (int ni = 0; ni < 4; ni++)
                acc[mi][ni] = __builtin_amdgcn_mfma_f32_16x16x32_bf16(af[mi], qf[kk][ni], acc[mi][ni], 0, 0, 0);
    }
}

// ---------------- cast fp32 -> bf16 (+ fused bias pack in tail blocks) ----------------
__global__ void cast_bf16_kernel(const float* __restrict__ in, u16* __restrict__ out, int n4,
                                 const float* __restrict__ bq, const float* __restrict__ bk,
                                 const float* __restrict__ bv, float* __restrict__ pb) {
    if (blockIdx.x >= 2048) {
        int j = (blockIdx.x - 2048) * 256 + threadIdx.x;  // 0..12287
        const float* s = j < 4096 ? bq : (j < 8192 ? bk : bv);
        pb[j] = s[j & 4095];
        return;
    }
    int i = blockIdx.x * blockDim.x + threadIdx.x;
    if (i >= n4) return;
    float4 v = ((const float4*)in)[i];
    ushort4 o;
    o.x = f2bf_bits(v.x); o.y = f2bf_bits(v.y); o.z = f2bf_bits(v.z); o.w = f2bf_bits(v.w);
    ((ushort4*)out)[i] = o;
}

// ---------------- merged transpose+cast: wq,wk,wv,wo + w1 + w2, one launch ----------------
// grid 24576 blocks of (32,8): [0,8192) wqkv/wo 512x512, [8192,16384) w1 512x2048, rest w2 2048x512
__global__ void transpose_all_kernel(const float* __restrict__ wq, const float* __restrict__ wk,
                                     const float* __restrict__ wv, const float* __restrict__ wo,
                                     const float* __restrict__ w1, const float* __restrict__ w2,
                                     u16* __restrict__ WB) {
    __shared__ float tile[32][33];
    const int bid = blockIdx.x;
    const float* s; u16* d; int R, C, c0, r0;
    if (bid < 8192) {
        int x = bid & 15, y = (bid >> 4) & 15, z = bid >> 8;
        s = (z < 8 ? wq : z < 16 ? wk : z < 24 ? wv : wo) + (long)(z & 7) * 262144;
        d = WB + (long)z * 262144;
        R = 512; C = 512; c0 = x * 32; r0 = y * 32;
    } else if (bid < 16384) {
        int idx = bid - 8192;
        int x = idx & 63, y = (idx >> 6) & 15, z = idx >> 10;
        s = w1 + (long)z * 1048576;
        d = WB + 8388608 + (long)z * 1048576;
        R = 512; C = 2048; c0 = x * 32; r0 = y * 32;
    } else {
        int idx = bid - 16384;
        int x = idx & 15, y = (idx >> 4) & 63, z = idx >> 10;
        s = w2 + (long)z * 1048576;
        d = WB + 16777216 + (long)z * 1048576;
        R = 2048; C = 512; c0 = x * 32; r0 = y * 32;
    }
    int tx = threadIdx.x, ty = threadIdx.y;
    #pragma unroll
    for (int i = 0; i < 4; i++)
        tile[ty + 8*i][tx] = s[(long)(r0 + ty + 8*i) * C + c0 + tx];
    __syncthreads();
    #pragma unroll
    for (int i = 0; i < 4; i++)
        d[(long)(c0 + ty + 8*i) * R + r0 + tx] = f2bf_bits(tile[tx][ty + 8*i]);
}

// ---------------- router ----------------
__global__ __launch_bounds__(512)
void router_kernel(const float* __restrict__ x, const float* __restrict__ gw,
                   const float* __restrict__ gb, float* __restrict__ rw,
                   float* __restrict__ logits_out) {
    int row = blockIdx.x;
    int w = threadIdx.x >> 6;
    int lane = threadIdx.x & 63;
    const float* xr = x + (long)row * 512;
    float sum = 0.f;
    #pragma unroll
    for (int i = 0; i < 8; i++) {
        int d = lane + 64 * i;
        sum += xr[d] * gw[d * 8 + w];
    }
    #pragma unroll
    for (int o = 32; o; o >>= 1) sum += __shfl_down(sum, o, 64);
    __shared__ float lg[8];
    if (lane == 0) lg[w] = sum + gb[w];
    __syncthreads();
    if (threadIdx.x == 0) {
        float l[8];
        #pragma unroll
        for (int e = 0; e < 8; e++) l[e] = lg[e];
        int i1 = 0;
        for (int e = 1; e < 8; e++) if (l[e] > l[i1]) i1 = e;
        int i2 = -1;
        for (int e = 0; e < 8; e++) { if (e == i1) continue; if (i2 < 0 || l[e] > l[i2]) i2 = e; }
        for (int e = 0; e < 8; e++) {
            float v = (e == i1 || e == i2) ? (l[e] > 0.f ? l[e] : 0.f) : 0.f;
            float r = 0.f, mem = v;
            #pragma unroll
            for (int lvl = 0; lvl < 4; lvl++) {
                float thr = 4.0f / (float)(1 << lvl);
                if (mem >= thr) { r += thr; mem -= thr; }
            }
            rw[(long)row * 8 + e] = r;
            logits_out[(long)row * 8 + e] = l[e];
        }
    }
}

// ---------------- build packed row space: per b, experts packed back-to-back ----------------
__global__ __launch_bounds__(256)
void build_lists_kernel(const float* __restrict__ rw, int* __restrict__ prix,
                        int* __restrict__ act, int* __restrict__ smap,
                        int* __restrict__ tmap, int* __restrict__ tt, int* __restrict__ pt) {
    int b = blockIdx.x;
    int t = threadIdx.x, wv = t >> 6, lane = t & 63;
    __shared__ int wsum[4];
    __shared__ int base_sh;
    if (t == 0) base_sh = 0;
    __syncthreads();
    for (int e = 0; e < 8; e++) {
        int r0 = b * 1024 + t * 4;
        int f[4], c = 0;
        #pragma unroll
        for (int i = 0; i < 4; i++) {
            f[i] = (rw[(long)(r0 + i) * 8 + e] != 0.f) ? 1 : 0;
            c += f[i];
        }
        int incl = c;
        #pragma unroll
        for (int o = 1; o < 64; o <<= 1) {
            int n = __shfl_up(incl, o, 64);
            if (lane >= o) incl += n;
        }
        if (lane == 63) wsum[wv] = incl;
        __syncthreads();
        int woff = 0;
        #pragma unroll
        for (int k = 0; k < 4; k++) if (k < wv) woff += wsum[k];
        int tot = wsum[0] + wsum[1] + wsum[2] + wsum[3];
        int excl = incl - c + woff;
        int base = base_sh;
        int slot = excl;
        #pragma unroll
        for (int i = 0; i < 4; i++) {
            int r = r0 + i;
            if (f[i]) {
                int ps = base + slot;
                prix[b * 3072 + ps] = r;
                act[b * 3072 + ps] = 1;
                smap[(long)r * 8 + e] = ps;
                slot++;
            } else {
                smap[(long)r * 8 + e] = -1;
            }
        }
        int pad = (tot + 127) & ~127;
        for (int s = tot + t; s < pad; s += 256) {
            prix[b * 3072 + base + s] = b * 1024;
            act[b * 3072 + base + s] = 0;
        }
        for (int k = t; k < (pad >> 7); k += 256)
            tmap[b * 32 + (base >> 7) + k] = e;
        __syncthreads();
        if (t == 0) base_sh = base + pad;
        __syncthreads();
    }
    if (t == 0) {
        tt[b] = base_sh >> 7;
        pt[b] = base_sh;
    }
}

// ---------------- merged K/V dense + packed-Q GEMM, one launch (tail-fill) ----------------
// 1D grid 2432 blocks: [0,2048) KV (x=bid&3, y=(bid>>2)&31, z=bid>>7; z<8 K, z>=8 V-transposed);
// [2048,2432): Qp packed-gather GEMM (x=idx&3, y=idx>>2 -> b,tile).
__global__ __launch_bounds__(256)
void gemm_kvq_kernel(const u16* __restrict__ XB, const u16* __restrict__ Wkv,
                     u16* __restrict__ CK, u16* __restrict__ CV,
                     const float* __restrict__ biasKV,
                     const u16* __restrict__ Wq, u16* __restrict__ QP,
                     const float* __restrict__ biasQ,
                     const int* __restrict__ tmap, const int* __restrict__ tt,
                     const int* __restrict__ prix) {
    __shared__ __align__(16) u16 As[2][128 * 64];
    __shared__ __align__(16) u16 Bs[2][128 * 64];
    const int tid = threadIdx.x;
    const int w = tid >> 6, lane = tid & 63;
    const int wy = w >> 1, wx = w & 1;
    const int quad = lane >> 4, mrow = lane & 15;
    const int bid = blockIdx.x;

    if (bid < 2048) {
        const int bx = bid & 3, by = (bid >> 2) & 31, z = bid >> 7;
        const u16* Bb = Wkv + (long)z * 262144 + (long)bx * 128 * 512;

        long arow[4];
        #pragma unroll
        for (int j = 0; j < 4; ++j) arow[j] = (long)by * 128 + ((j * 256 + tid) >> 3);

        floatx4 acc[4][4];
        #pragma unroll
        for (int i = 0; i < 4; i++)
            #pragma unroll
            for (int j = 0; j < 4; j++)
                acc[i][j] = floatx4{0.f, 0.f, 0.f, 0.f};

        stage64(XB, 512, arow, Bb, 512, 0, tid, As[0], Bs[0]);
        for (int it = 0; it < 8; ++it) {
            const int cur = it & 1;
            __syncthreads();
            if (it + 1 < 8)
                stage64(XB, 512, arow, Bb, 512, (it + 1) << 6, tid, As[1 - cur], Bs[1 - cur]);
            compute64(As[cur], Bs[cur], wy, wx, quad, mrow, acc);
        }

        const float* biasb = biasKV + (long)z * 512 + bx * 128;
        if (z >= 8) {   // V: transposed C into VT layout
            u16* Cb = CV + (long)(z - 8) * 2097152;
            #pragma unroll
            for (int ni = 0; ni < 4; ni++) {
                const int colt = wx * 64 + ni * 16 + mrow;
                const int n = bx * 128 + colt;
                float bv = biasb[colt];
                #pragma unroll
                for (int mi = 0; mi < 4; mi++) {
                    #pragma unroll
                    for (int r = 0; r < 4; r++) {
                        const int m = by * 128 + wy * 64 + mi * 16 + quad * 4 + r;
                        float v = acc[mi][ni][r] + bv;
                        long addr = ((long)(((m >> 10) << 2) + (n >> 7)) * 128 + (n & 127)) * 1024 + (m & 1023);
                        Cb[addr] = f2bf_bits(v);
                    }
                }
            }
        } else {        // K: normal row-major C
            u16* Cb = CK + (long)z * 2097152 + (long)by * 128 * 512 + bx * 128;
            #pragma unroll
            for (int ni = 0; ni < 4; ni++) {
                const int col = wx * 64 + ni * 16 + mrow;
                float bv = biasb[col];
                #pragma unroll
                for (int mi = 0; mi < 4; mi++) {
                    #pragma unroll
                    for (int r = 0; r < 4; r++) {
                        const int row = wy * 64 + mi * 16 + quad * 4 + r;
                        Cb[(long)row * 512 + col] = f2bf_bits(acc[mi][ni][r] + bv);
                    }
                }
            }
        }
    } else {
        const int idx = bid - 2048;
        const int bx = idx & 3, yy = idx >> 2;
        const int b = yy / 24, tile = yy % 24;
        if (tile >= tt[b]) return;
        const int e = tmap[b * 32 + tile];
        const long rbase = (long)b * 3072 + tile * 128;
        const u16* Bb = Wq + (long)e * 262144 + (long)bx * 128 * 512;

        long arow[4];
        #pragma unroll
        for (int j = 0; j < 4; ++j)
            arow[j] = (long)prix[b * 3072 + tile * 128 + ((j * 256 + tid) >> 3)];

        floatx4 acc[4][4];
        #pragma unroll
        for (int i = 0; i < 4; i++)
            #pragma unroll
            for (int j = 0; j < 4; j++)
                acc[i][j] = floatx4{0.f, 0.f, 0.f, 0.f};

        stage64(XB, 512, arow, Bb, 512, 0, tid, As[0], Bs[0]);
        for (int it = 0; it < 8; ++it) {
            const int cur = it & 1;
            __syncthreads();
            if (it + 1 < 8)
                stage64(XB, 512, arow, Bb, 512, (it + 1) << 6, tid, As[1 - cur], Bs[1 - cur]);
            compute64(As[cur], Bs[cur], wy, wx, quad, mrow, acc);
        }

        u16* Cb = QP + rbase * 512 + bx * 128;
        const float* biasb = biasQ + bx * 128;
        #pragma unroll
        for (int ni = 0; ni < 4; ni++) {
            const int col = wx * 64 + ni * 16 + mrow;
            float bv = biasb[col];
            #pragma unroll
            for (int mi = 0; mi < 4; mi++) {
                #pragma unroll
                for (int r = 0; r < 4; r++) {
                    const int row = wy * 64 + mi * 16 + quad * 4 + r;
                    Cb[(long)row * 512 + col] = f2bf_bits(acc[mi][ni][r] + bv);
                }
            }
        }
    }
}

// ---------------- fused attention: S^T = K@Q^T -> exp -> P@V, no S round trip (R2-proven) ----------------
// grid x=24 (packed tiles), y=16 (b*4+h). OC block-exclusively aliases QP (read-before-write).
__global__ __launch_bounds__(256, 2)
void attn_fused_kernel(const u16* __restrict__ QP, const u16* __restrict__ Km,
                       const u16* __restrict__ VT, u16* __restrict__ OC,
                       const int* __restrict__ tmap, const int* __restrict__ tt, float alpha) {
    const int tile = blockIdx.x;
    const int bh = blockIdx.y;
    const int b = bh >> 2, h = bh & 3;
    if (tile >= tt[b]) return;
    const int e = tmap[b * 32 + tile];

    __shared__ __align__(16) u16 Bs[2][128 * 64];   // K-tile, then V-tile
    __shared__ __align__(16) u16 Ps[2][128 * 64];   // Q staging, then P (B-operand layout)
    __shared__ float rs_sh[2][128];

    const int tid = threadIdx.x;
    const int w = tid >> 6, lane = tid & 63;
    const int wy = w >> 1, wx = w & 1;
    const int quad = lane >> 4, mrow = lane & 15;

    const u16* Qbase = QP + ((long)b * 3072 + tile * 128) * 512 + h * 128;
    const u16* Kbase = Km + ((long)e * 4096 + b * 1024) * 512 + h * 128;
    const u16* Vbase = VT + ((long)e * 16 + bh) * 131072;

    // prologue: stage Q into Ps, then pull fragments into registers
    stage_one(Qbase, 512, tid, Ps[0]);
    stage_one(Qbase + 64, 512, tid, Ps[1]);
    __syncthreads();
    bfv8 qf[2][2][4];
    #pragma unroll
    for (int c = 0; c < 2; c++)
        #pragma unroll
        for (int kk = 0; kk < 2; kk++)
            #pragma unroll
            for (int ni = 0; ni < 4; ni++) {
                const int r = wx * 64 + ni * 16 + mrow;
                const int slot = (kk * 4 + quad) ^ (r & 7);
                qf[c][kk][ni] = *(const bfv8*)&Ps[c][r * 64 + slot * 8];
            }

    floatx4 acc_o[4][4];
    float rsum[4];
    #pragma unroll
    for (int i = 0; i < 4; i++) {
        rsum[i] = 0.f;
        #pragma unroll
        for (int j = 0; j < 4; j++) acc_o[i][j] = floatx4{0.f, 0.f, 0.f, 0.f};
    }

    for (int kt = 0; kt < 8; ++kt) {
        __syncthreads();                       // Bs + Ps free (prev PV reads done; kt=0: qf loaded)
        stage_one(Kbase + (long)kt * 128 * 512,      512, tid, Bs[0]);
        stage_one(Kbase + (long)kt * 128 * 512 + 64, 512, tid, Bs[1]);
        __syncthreads();                       // K ready

        floatx4 acc_s[4][4];
        #pragma unroll
        for (int i = 0; i < 4; i++)
            #pragma unroll
            for (int j = 0; j < 4; j++) acc_s[i][j] = floatx4{0.f, 0.f, 0.f, 0.f};
        computeQK(Bs[0], qf[0], wy, quad, mrow, acc_s);
        computeQK(Bs[1], qf[1], wy, quad, mrow, acc_s);

        // p = exp(alpha*s); per-lane row sums (cols = queries are lane-local in S^T layout)
        #pragma unroll
        for (int mi = 0; mi < 4; mi++)
            #pragma unroll
            for (int ni = 0; ni < 4; ni++)
                #pragma unroll
                for (int r = 0; r < 4; r++) {
                    float p = __expf(acc_s[mi][ni][r] * alpha);
                    acc_s[mi][ni][r] = p;
                    rsum[ni] += p;
                }

        __syncthreads();                       // all QK reads of Bs done
        stage_one(Vbase + kt * 128,      1024, tid, Bs[0]);
        stage_one(Vbase + kt * 128 + 64, 1024, tid, Bs[1]);
        // write P into Ps as B-operand [query][key-chunk], chunk = wy; packed b32 pairs
        u16* Pw = Ps[wy];
        #pragma unroll
        for (int mi = 0; mi < 4; mi++) {
            const int sb = mi * 2 + (quad >> 1);
            #pragma unroll
            for (int ni = 0; ni < 4; ni++) {
                const int q = wx * 64 + ni * 16 + mrow;
                u16* pr = Pw + q * 64 + (sb ^ (q & 7)) * 8 + (quad & 1) * 4;
                #pragma unroll
                for (int r = 0; r < 4; r += 2) {
                    uint32_t pk = (uint32_t)f2bf_bits(acc_s[mi][ni][r]) |
                                  ((uint32_t)f2bf_bits(acc_s[mi][ni][r + 1]) << 16);
                    *(uint32_t*)(pr + r) = pk;
                }
            }
        }
        __syncthreads();                       // V + P ready
        compute64(Bs[0], Ps[0], wy, wx, quad, mrow, acc_o);   // O^T += V^T @ P^T
        compute64(Bs[1], Ps[1], wy, wx, quad, mrow, acc_o);
    }

    // row sums: reduce over quad lanes, then across wy waves via LDS
    #pragma unroll
    for (int ni = 0; ni < 4; ni++) {
        float v = rsum[ni];
        v += __shfl_xor(v, 16, 64);
        v += __shfl_xor(v, 32, 64);
        if (quad == 0) rs_sh[wy][wx * 64 + ni * 16 + mrow] = v;
    }
    __syncthreads();
    u16* Cb = OC + ((long)b * 3072 + tile * 128) * 512 + h * 128;
    #pragma unroll
    for (int ni = 0; ni < 4; ni++) {
        const int q = wx * 64 + ni * 16 + mrow;
        const float inv = 1.f / (rs_sh[0][q] + rs_sh[1][q]);
        #pragma unroll
        for (int mi = 0; mi < 4; mi++) {
            ushort4 st;
            st.x = f2bf_bits(acc_o[mi][ni][0] * inv);
            st.y = f2bf_bits(acc_o[mi][ni][1] * inv);
            st.z = f2bf_bits(acc_o[mi][ni][2] * inv);
            st.w = f2bf_bits(acc_o[mi][ni][3] * inv);
            *(ushort4*)(Cb + (long)q * 512 + wy * 64 + mi * 16 + quad * 4) = st;
        }
    }
}

// ---------------- packed GEMM (Wo / FFN1): per-tile expert weights ----------------
// grid x = N/128, y = 96 (b = y/24, tile = y%24)
template<bool RELU>
__global__ __launch_bounds__(256)
void gemm_packed_kernel(const u16* __restrict__ A, int lda,
                        const u16* __restrict__ B, int ldb, long sBe,
                        u16* __restrict__ C, int ldc,
                        const float* __restrict__ bias, long sBiasE,
                        const int* __restrict__ tmap, const int* __restrict__ tt, int K) {
    const int b = blockIdx.y / 24, tile = blockIdx.y % 24;
    if (tile >= tt[b]) return;
    const int e = tmap[b * 32 + tile];
    __shared__ __align__(16) u16 As[2][128 * 64];
    __shared__ __align__(16) u16 Bs[2][128 * 64];
    const long rbase = (long)b * 3072 + tile * 128;
    const u16* Ab = A + rbase * lda;
    const u16* Bb = B + (long)e * sBe + (long)blockIdx.x * 128 * ldb;

    const int tid = threadIdx.x;
    const int w = tid >> 6, lane = tid & 63;
    const int wy = w >> 1, wx = w & 1;
    const int quad = lane >> 4, mrow = lane & 15;

    long arow[4];
    #pragma unroll
    for (int j = 0; j < 4; ++j) arow[j] = (j * 256 + tid) >> 3;

    floatx4 acc[4][4];
    #pragma unroll
    for (int i = 0; i < 4; i++)
        #pragma unroll
        for (int j = 0; j < 4; j++)
            acc[i][j] = floatx4{0.f, 0.f, 0.f, 0.f};

    const int nk = K >> 6;
    stage64(Ab, lda, arow, Bb, ldb, 0, tid, As[0], Bs[0]);
    for (int it = 0; it < nk; ++it) {
        const int cur = it & 1;
        __syncthreads();
        if (it + 1 < nk)
            stage64(Ab, lda, arow, Bb, ldb, (it + 1) << 6, tid, As[1 - cur], Bs[1 - cur]);
        compute64(As[cur], Bs[cur], wy, wx, quad, mrow, acc);
    }

    u16* Cb = C + rbase * ldc + (long)blockIdx.x * 128;
    const float* biasb = bias + (long)e * sBiasE + blockIdx.x * 128;
    #pragma unroll
    for (int ni = 0; ni < 4; ni++) {
        const int col = wx * 64 + ni * 16 + mrow;
        float bv = biasb[col];
        #pragma unroll
        for (int mi = 0; mi < 4; mi++) {
            #pragma unroll
            for (int r = 0; r < 4; r++) {
                const int row = wy * 64 + mi * 16 + quad * 4 + r;
                float v = acc[mi][ni][r] + bv;
                if (RELU) v = fmaxf(v, 0.f);
                Cb[(long)row * ldc + col] = f2bf_bits(v);
            }
        }
    }
}

// ---------------- FFN2 K-split: z=0 keys [0,1024), z=1 [1024,2048); f32 partials, no bias ----------------
// grid (4, 96, 2)
__global__ __launch_bounds__(256)
void gemm_ffn2_half_kernel(const u16* __restrict__ MID, const u16* __restrict__ W2T,
                           float* __restrict__ P0, float* __restrict__ P1,
                           const int* __restrict__ tmap, const int* __restrict__ tt) {
    const int b = blockIdx.y / 24, tile = blockIdx.y % 24;
    if (tile >= tt[b]) return;
    const int e = tmap[b * 32 + tile];
    __shared__ __align__(16) u16 As[2][128 * 64];
    __shared__ __align__(16) u16 Bs[2][128 * 64];
    const long rbase = (long)b * 3072 + tile * 128;
    const int koff = blockIdx.z * 1024;
    const u16* Ab = MID + rbase * 2048 + koff;
    const u16* Bb = W2T + (long)e * 1048576 + (long)blockIdx.x * 128 * 2048 + koff;

    const int tid = threadIdx.x;
    const int w = tid >> 6, lane = tid & 63;
    const int wy = w >> 1, wx = w & 1;
    const int quad = lane >> 4, mrow = lane & 15;

    long arow[4];
    #pragma unroll
    for (int j = 0; j < 4; ++j) arow[j] = (j * 256 + tid) >> 3;

    floatx4 acc[4][4];
    #pragma unroll
    for (int i = 0; i < 4; i++)
        #pragma unroll
        for (int j = 0; j < 4; j++)
            acc[i][j] = floatx4{0.f, 0.f, 0.f, 0.f};

    stage64(Ab, 2048, arow, Bb, 2048, 0, tid, As[0], Bs[0]);
    for (int it = 0; it < 16; ++it) {
        const int cur = it & 1;
        __syncthreads();
        if (it + 1 < 16)
            stage64(Ab, 2048, arow, Bb, 2048, (it + 1) << 6, tid, As[1 - cur], Bs[1 - cur]);
        compute64(As[cur], Bs[cur], wy, wx, quad, mrow, acc);
    }

    float* Cb = (blockIdx.z ? P1 : P0) + rbase * 512 + (long)blockIdx.x * 128;
    #pragma unroll
    for (int ni = 0; ni < 4; ni++) {
        const int col = wx * 64 + ni * 16 + mrow;
        #pragma unroll
        for (int mi = 0; mi < 4; mi++) {
            #pragma unroll
            for (int r = 0; r < 4; r++) {
                const int row = wy * 64 + mi * 16 + quad * 4 + r;
                Cb[(long)row * 512 + col] = acc[mi][ni][r];
            }
        }
    }
}

// ---------------- LN1 on packed rows ----------------
__global__ __launch_bounds__(128)
void ln1_kernel(const float* __restrict__ x, const u16* __restrict__ tc,
                const int* __restrict__ prix, const int* __restrict__ act,
                const int* __restrict__ tmap, const int* __restrict__ pt,
                const float* __restrict__ s_all, const float* __restrict__ b_all,
                u16* __restrict__ hb) {
    int blk = blockIdx.x;
    int b = blk / 3072, pslot = blk % 3072;
    if (pslot >= pt[b]) return;
    long row = (long)b * 3072 + pslot;
    int tid = threadIdx.x, w = tid >> 6, lane = tid & 63;
    if (!act[row]) {
        *(ushort4*)(hb + row * 512 + tid * 4) = make_ushort4(0, 0, 0, 0);
        return;
    }
    int r = prix[row];
    int e = tmap[b * 32 + (pslot >> 7)];
    float4 xv = *(const float4*)(x + (long)r * 512 + tid * 4);
    ushort4 tu = *(const ushort4*)(tc + row * 512 + tid * 4);
    float v[4] = {xv.x + bf_bits2f(tu.x), xv.y + bf_bits2f(tu.y),
                  xv.z + bf_bits2f(tu.z), xv.w + bf_bits2f(tu.w)};
    float sum = v[0] + v[1] + v[2] + v[3];
    #pragma unroll
    for (int o = 32; o; o >>= 1) sum += __shfl_down(sum, o, 64);
    __shared__ float sh[4];
    if (lane == 0) sh[w] = sum;
    __syncthreads();
    float mu = (sh[0] + sh[1]) * (1.f / 512.f);
    float sq = 0.f;
    #pragma unroll
    for (int j = 0; j < 4; j++) { float d = v[j] - mu; sq += d * d; }
    #pragma unroll
    for (int o = 32; o; o >>= 1) sq += __shfl_down(sq, o, 64);
    if (lane == 0) sh[2 + w] = sq;
    __syncthreads();
    float inv = 1.f / sqrtf((sh[2] + sh[3]) * (1.f / 512.f) + 1e-5f);
    float4 sv = *(const float4*)(s_all + e * 512 + tid * 4);
    float4 bv = *(const float4*)(b_all + e * 512 + tid * 4);
    ushort4 ub;
    ub.x = f2bf_bits((v[0] - mu) * inv * sv.x + bv.x);
    ub.y = f2bf_bits((v[1] - mu) * inv * sv.y + bv.y);
    ub.z = f2bf_bits((v[2] - mu) * inv * sv.z + bv.z);
    ub.w = f2bf_bits((v[3] - mu) * inv * sv.w + bv.w);
    *(ushort4*)(hb + row * 512 + tid * 4) = ub;
}

// ---------------- LN2 + FFN2 partial-sum + bias + weighted accumulate over all 8 experts ----------------
__global__ __launch_bounds__(128)
void ln2acc_kernel(const u16* __restrict__ hb, const float* __restrict__ p0,
                   const float* __restrict__ p1, const float* __restrict__ b2,
                   const float* __restrict__ s_all, const float* __restrict__ b_all,
                   const float* __restrict__ rw, const int* __restrict__ smap,
                   float* __restrict__ out) {
    long r = blockIdx.x;
    int b = (int)(r >> 10);
    int tid = threadIdx.x, w = tid >> 6, lane = tid & 63;
    __shared__ float sh[4];
    float4 acc = make_float4(0.f, 0.f, 0.f, 0.f);
    for (int e = 0; e < 8; e++) {
        int ps = smap[r * 8 + e];
        if (ps >= 0) {   // block-uniform
            float wgt = rw[r * 8 + e];
            long row = (long)b * 3072 + ps;
            ushort4 hu = *(const ushort4*)(hb + row * 512 + tid * 4);
            float4 f0 = *(const float4*)(p0 + row * 512 + tid * 4);
            float4 f1 = *(const float4*)(p1 + row * 512 + tid * 4);
            float4 bb = *(const float4*)(b2 + (long)e * 512 + tid * 4);
            float v[4] = {bf_bits2f(hu.x) + f0.x + f1.x + bb.x,
                          bf_bits2f(hu.y) + f0.y + f1.y + bb.y,
                          bf_bits2f(hu.z) + f0.z + f1.z + bb.z,
                          bf_bits2f(hu.w) + f0.w + f1.w + bb.w};
            float sum = v[0] + v[1] + v[2] + v[3];
            #pragma unroll
            for (int o = 32; o; o >>= 1) sum += __shfl_down(sum, o, 64);
            if (lane == 0) sh[w] = sum;
            __syncthreads();
            float mu = (sh[0] + sh[1]) * (1.f / 512.f);
            float sq = 0.f;
            #pragma unroll
            for (int j = 0; j < 4; j++) { float d = v[j] - mu; sq += d * d; }
            #pragma unroll
            for (int o = 32; o; o >>= 1) sq += __shfl_down(sq, o, 64);
            if (lane == 0) sh[2 + w] = sq;
            __syncthreads();
            float inv = 1.f / sqrtf((sh[2] + sh[3]) * (1.f / 512.f) + 1e-5f);
            float4 sv = *(const float4*)(s_all + e * 512 + tid * 4);
            float4 bv = *(const float4*)(b_all + e * 512 + tid * 4);
            acc.x += wgt * ((v[0] - mu) * inv * sv.x + bv.x);
            acc.y += wgt * ((v[1] - mu) * inv * sv.y + bv.y);
            acc.z += wgt * ((v[2] - mu) * inv * sv.z + bv.z);
            acc.w += wgt * ((v[3] - mu) * inv * sv.w + bv.w);
            __syncthreads();
        }
    }
    *(float4*)(out + r * 512 + tid * 4) = acc;
}

// ---------------- workspace layout (bytes), ws_size = 256 MiB ----------------
static const size_t WB_B   = 0;           // 48 MiB: wq,wk,wv,wo (8x262144 each), w1 (8x1048576), w2 (8x1048576)
static const size_t RW_B   = 50331648;    // f32 [4096][8]
static const size_t PB_B   = 50462720;    // f32 [3][8][512]
static const size_t TT_B   = 50511872;    // i32[4] tiles per b
static const size_t PT_B   = 50511888;    // i32[4] packed rows per b
static const size_t TMAP_B = 50511904;    // i32 [4][32]
static const size_t PRIX_B = 50512416;    // i32 [4][3072]
static const size_t ACT_B  = 50561568;    // i32 [4][3072]
static const size_t SMAP_B = 50610720;    // i32 [4096][8]
static const size_t XB_B   = 50741792;    // bf16 [4096][512]
static const size_t Q8_B   = 54936096;    // bf16 packed Q [4][3072][512] (12.6 MiB)
static const size_t K8_B   = 88490528;    // bf16 [8][4096][512] (32 MiB)
static const size_t VT_B   = 122044960;   // bf16 [8][16][128][1024] (32 MiB)
static const size_t S_B    = 155599392;   // scratch: FFN mid bf16 [4][3072][2048] (50.3 MiB)
static const size_t OC_B   = Q8_B;        // fused attn out: block-exclusive alias of QP
static const size_t TC_B   = K8_B;        // bf16 [4][3072][512] — K dead after attn
static const size_t HB_B   = Q8_B;        // LN1 out — OC dead after Wo
static const size_t MID_B  = S_B;         // ends at 205,931,040
static const size_t FP0_B  = VT_B;        // f32 [4][3072][512] = 25.2 MiB — VT dead after attn
static const size_t FP1_B  = 205931040;   // f32 [4][3072][512], ends 231,096,864 < 268,435,456

extern "C" void kernel_launch(void* const* d_in, const int* in_sizes, int n_in,
                              void* d_out, int out_size, void* d_ws, size_t ws_size,
                              hipStream_t stream) {
    const float* x      = (const float*)d_in[0];
    const float* gate_w = (const float*)d_in[1];
    const float* gate_b = (const float*)d_in[2];
    const float* ln1_s  = (const float*)d_in[3];
    const float* ln1_b  = (const float*)d_in[4];
    const float* ln2_s  = (const float*)d_in[5];
    const float* ln2_b  = (const float*)d_in[6];
    const float* wq = (const float*)d_in[7];
    const float* wk = (const float*)d_in[8];
    const float* wv = (const float*)d_in[9];
    const float* wo = (const float*)d_in[10];
    const float* bo = (const float*)d_in[14];
    const float* w1 = (const float*)d_in[15];
    const float* b1 = (const float*)d_in[16];
    const float* w2 = (const float*)d_in[17];
    const float* b2 = (const float*)d_in[18];
    float* out = (float*)d_out;

    char* ws = (char*)d_ws;
    u16*   WB   = (u16*)(ws + WB_B);
    float* RW   = (float*)(ws + RW_B);
    float* PB   = (float*)(ws + PB_B);
    int*   TT   = (int*)(ws + TT_B);
    int*   PT   = (int*)(ws + PT_B);
    int*   TMAP = (int*)(ws + TMAP_B);
    int*   PRIX = (int*)(ws + PRIX_B);
    int*   ACT  = (int*)(ws + ACT_B);
    int*   SMAP = (int*)(ws + SMAP_B);
    u16*   XB   = (u16*)(ws + XB_B);
    u16*   QP   = (u16*)(ws + Q8_B);
    u16*   K8   = (u16*)(ws + K8_B);
    u16*   VT8  = (u16*)(ws + VT_B);
    u16*   OC   = (u16*)(ws + OC_B);
    u16*   TC   = (u16*)(ws + TC_B);
    u16*   HB   = (u16*)(ws + HB_B);
    u16*   MID  = (u16*)(ws + MID_B);
    float* FP0  = (float*)(ws + FP0_B);
    float* FP1  = (float*)(ws + FP1_B);

    // ---- setup ----
    cast_bf16_kernel<<<dim3(2096), 256, 0, stream>>>(x, XB, 4096 * 512 / 4,
                                                     (const float*)d_in[11], (const float*)d_in[12],
                                                     (const float*)d_in[13], PB);
    transpose_all_kernel<<<dim3(24576), dim3(32,8), 0, stream>>>(wq, wk, wv, wo, w1, w2, WB);
    router_kernel<<<4096, 512, 0, stream>>>(x, gate_w, gate_b, RW, out + 2097152);
    build_lists_kernel<<<4, 256, 0, stream>>>(RW, PRIX, ACT, SMAP, TMAP, TT, PT);

    const float isq = 0.08838834764831845f;  // 1/sqrt(128)

    // ---- K + V (dense, 2048 blocks) + Qp (packed gather, 384 blocks) in one tail-filled launch ----
    gemm_kvq_kernel<<<dim3(2432), 256, 0, stream>>>(
        XB, WB + 2097152, K8, VT8, PB + 4096, WB, QP, PB, TMAP, TT, PRIX);

    // ---- fused attention (R2-proven structure, 8 x 128-key steps) ----
    attn_fused_kernel<<<dim3(24, 16), 256, 0, stream>>>(QP, K8, VT8, OC, TMAP, TT, isq);

    // ---- Wo ----
    gemm_packed_kernel<false><<<dim3(4,96), 256, 0, stream>>>(
        OC, 512, WB + 6291456, 512, 262144, TC, 512, bo, 512, TMAP, TT, 512);
    // ---- LN1 ----
    ln1_kernel<<<12288, 128, 0, stream>>>(x, TC, PRIX, ACT, TMAP, PT, ln1_s, ln1_b, HB);
    // ---- FFN1 ----
    gemm_packed_kernel<true><<<dim3(16,96), 256, 0, stream>>>(
        HB, 512, WB + 8388608, 512, 1048576, MID, 2048, b1, 2048, TMAP, TT, 512);
    // ---- FFN2, K-split halves into f32 partials (2x occupancy) ----
    gemm_ffn2_half_kernel<<<dim3(4,96,2), 256, 0, stream>>>(
        MID, WB + 16777216, FP0, FP1, TMAP, TT);
    // ---- LN2 + partial-sum + bias + routing-weighted accumulate ----
    ln2acc_kernel<<<4096, 128, 0, stream>>>(HB, FP0, FP1, b2, ln2_s, ln2_b, RW, SMAP, out);
}

// Round 9
// 419.621 us; speedup vs baseline: 1.0695x; 1.0695x over previous
//
#include <hip/hip_runtime.h>
#include <hip/hip_bf16.h>
#include <stdint.h>

using u16 = unsigned short;
typedef float floatx4 __attribute__((ext_vector_type(4)));
typedef __bf16 bfv8 __attribute__((ext_vector_type(8)));

#define AS1 __attribute__((address_space(1)))
#define AS3 __attribute__((address_space(3)))

__device__ __forceinline__ u16 f2bf_bits(float f) {
    __hip_bfloat16 h = __float2bfloat16(f);
    u16 u;
    __builtin_memcpy(&u, &h, 2);
    return u;
}
__device__ __forceinline__ float bf_bits2f(u16 u) {
    __hip_bfloat16 h;
    __builtin_memcpy(&h, &u, 2);
    return __bfloat162float(h);
}
__device__ __forceinline__ void gload_lds16(const void* g, void* l) {
    __builtin_amdgcn_global_load_lds((AS1 void*)(uintptr_t)g, (AS3 void*)l, 16, 0, 0);
}

// ---- BK=64 tile staging (dbuf), XOR-swizzled chunks ----
__device__ __forceinline__ void stage64(const u16* __restrict__ Abase, long lda, const long* arow,
                                        const u16* __restrict__ Bb, long ldb, int k0, int tid,
                                        u16* Ad, u16* Bd) {
    #pragma unroll
    for (int j = 0; j < 4; ++j) {
        const int q   = j * 256 + tid;
        const int row = q >> 3;
        const int cg  = (q & 7) ^ (row & 7);
        gload_lds16(Abase + arow[j] * lda + k0 + cg * 8, Ad + q * 8);
        gload_lds16(Bb + (long)row * ldb + k0 + cg * 8, Bd + q * 8);
    }
}
// stage a single 128x64 chunk (contiguous rows)
__device__ __forceinline__ void stage_one(const u16* __restrict__ base, long ld, int tid, u16* dst) {
    #pragma unroll
    for (int j = 0; j < 4; ++j) {
        const int q   = j * 256 + tid;
        const int row = q >> 3;
        const int cg  = (q & 7) ^ (row & 7);
        gload_lds16(base + (long)row * ld + cg * 8, dst + q * 8);
    }
}
__device__ __forceinline__ void compute64(const u16* Ab, const u16* Bb, int wy, int wx,
                                          int quad, int mrow, floatx4 acc[4][4]) {
    #pragma unroll
    for (int kk = 0; kk < 2; ++kk) {
        bfv8 af[4], bf[4];
        #pragma unroll
        for (int mi = 0; mi < 4; mi++) {
            const int r = wy * 64 + mi * 16 + mrow;
            const int slot = (kk * 4 + quad) ^ (r & 7);
            af[mi] = *(const bfv8*)&Ab[r * 64 + slot * 8];
        }
        #pragma unroll
        for (int ni = 0; ni < 4; ni++) {
            const int r = wx * 64 + ni * 16 + mrow;
            const int slot = (kk * 4 + quad) ^ (r & 7);
            bf[ni] = *(const bfv8*)&Bb[r * 64 + slot * 8];
        }
        #pragma unroll
        for (int mi = 0; mi < 4; mi++)
            #pragma unroll
            for (int ni = 0; ni < 4; ni++)
                acc[mi][ni] = __builtin_amdgcn_mfma_f32_16x16x32_bf16(af[mi], bf[ni], acc[mi][ni], 0, 0, 0);
    }
}
// A from LDS (K-tile rows=keys), B from registers (Q fragments)
__device__ __forceinline__ void computeQK(const u16* Kb, const bfv8 qf[2][4], int wy,
                                          int quad, int mrow, floatx4 acc[4][4]) {
    #pragma unroll
    for (int kk = 0; kk < 2; ++kk) {
        bfv8 af[4];
        #pragma unroll
        for (int mi = 0; mi < 4; mi++) {
            const int r = wy * 64 + mi * 16 + mrow;
            const int slot = (kk * 4 + quad) ^ (r & 7);
            af[mi] = *(const bfv8*)&Kb[r * 64 + slot * 8];
        }
        #pragma unroll
        for (int mi = 0; mi < 4; mi++)
            #pragma unroll
            for (int ni = 0; ni < 4; ni++)
                acc[mi][ni] = __builtin_amdgcn_mfma_f32_16x16x32_bf16(af[mi], qf[kk][ni], acc[mi][ni], 0, 0, 0);
    }
}

// ---------------- cast fp32 -> bf16 (+ fused bias pack in tail blocks) ----------------
__global__ void cast_bf16_kernel(const float* __restrict__ in, u16* __restrict__ out, int n4,
                                 const float* __restrict__ bq, const float* __restrict__ bk,
                                 const float* __restrict__ bv, float* __restrict__ pb) {
    if (blockIdx.x >= 2048) {
        int j = (blockIdx.x - 2048) * 256 + threadIdx.x;  // 0..12287
        const float* s = j < 4096 ? bq : (j < 8192 ? bk : bv);
        pb[j] = s[j & 4095];
        return;
    }
    int i = blockIdx.x * blockDim.x + threadIdx.x;
    if (i >= n4) return;
    float4 v = ((const float4*)in)[i];
    ushort4 o;
    o.x = f2bf_bits(v.x); o.y = f2bf_bits(v.y); o.z = f2bf_bits(v.z); o.w = f2bf_bits(v.w);
    ((ushort4*)out)[i] = o;
}

// ---------------- merged transpose+cast: wq,wk,wv,wo + w1 + w2, one launch ----------------
// grid 24576 blocks of (32,8): [0,8192) wqkv/wo 512x512, [8192,16384) w1 512x2048, rest w2 2048x512
__global__ void transpose_all_kernel(const float* __restrict__ wq, const float* __restrict__ wk,
                                     const float* __restrict__ wv, const float* __restrict__ wo,
                                     const float* __restrict__ w1, const float* __restrict__ w2,
                                     u16* __restrict__ WB) {
    __shared__ float tile[32][33];
    const int bid = blockIdx.x;
    const float* s; u16* d; int R, C, c0, r0;
    if (bid < 8192) {
        int x = bid & 15, y = (bid >> 4) & 15, z = bid >> 8;
        s = (z < 8 ? wq : z < 16 ? wk : z < 24 ? wv : wo) + (long)(z & 7) * 262144;
        d = WB + (long)z * 262144;
        R = 512; C = 512; c0 = x * 32; r0 = y * 32;
    } else if (bid < 16384) {
        int idx = bid - 8192;
        int x = idx & 63, y = (idx >> 6) & 15, z = idx >> 10;
        s = w1 + (long)z * 1048576;
        d = WB + 8388608 + (long)z * 1048576;
        R = 512; C = 2048; c0 = x * 32; r0 = y * 32;
    } else {
        int idx = bid - 16384;
        int x = idx & 15, y = (idx >> 4) & 63, z = idx >> 10;
        s = w2 + (long)z * 1048576;
        d = WB + 16777216 + (long)z * 1048576;
        R = 2048; C = 512; c0 = x * 32; r0 = y * 32;
    }
    int tx = threadIdx.x, ty = threadIdx.y;
    #pragma unroll
    for (int i = 0; i < 4; i++)
        tile[ty + 8*i][tx] = s[(long)(r0 + ty + 8*i) * C + c0 + tx];
    __syncthreads();
    #pragma unroll
    for (int i = 0; i < 4; i++)
        d[(long)(c0 + ty + 8*i) * R + r0 + tx] = f2bf_bits(tile[tx][ty + 8*i]);
}

// ---------------- router ----------------
__global__ __launch_bounds__(512)
void router_kernel(const float* __restrict__ x, const float* __restrict__ gw,
                   const float* __restrict__ gb, float* __restrict__ rw,
                   float* __restrict__ logits_out) {
    int row = blockIdx.x;
    int w = threadIdx.x >> 6;
    int lane = threadIdx.x & 63;
    const float* xr = x + (long)row * 512;
    float sum = 0.f;
    #pragma unroll
    for (int i = 0; i < 8; i++) {
        int d = lane + 64 * i;
        sum += xr[d] * gw[d * 8 + w];
    }
    #pragma unroll
    for (int o = 32; o; o >>= 1) sum += __shfl_down(sum, o, 64);
    __shared__ float lg[8];
    if (lane == 0) lg[w] = sum + gb[w];
    __syncthreads();
    if (threadIdx.x == 0) {
        float l[8];
        #pragma unroll
        for (int e = 0; e < 8; e++) l[e] = lg[e];
        int i1 = 0;
        for (int e = 1; e < 8; e++) if (l[e] > l[i1]) i1 = e;
        int i2 = -1;
        for (int e = 0; e < 8; e++) { if (e == i1) continue; if (i2 < 0 || l[e] > l[i2]) i2 = e; }
        for (int e = 0; e < 8; e++) {
            float v = (e == i1 || e == i2) ? (l[e] > 0.f ? l[e] : 0.f) : 0.f;
            float r = 0.f, mem = v;
            #pragma unroll
            for (int lvl = 0; lvl < 4; lvl++) {
                float thr = 4.0f / (float)(1 << lvl);
                if (mem >= thr) { r += thr; mem -= thr; }
            }
            rw[(long)row * 8 + e] = r;
            logits_out[(long)row * 8 + e] = l[e];
        }
    }
}

// ---------------- build packed row space: per b, experts packed back-to-back ----------------
__global__ __launch_bounds__(256)
void build_lists_kernel(const float* __restrict__ rw, int* __restrict__ prix,
                        int* __restrict__ act, int* __restrict__ smap,
                        int* __restrict__ tmap, int* __restrict__ tt, int* __restrict__ pt) {
    int b = blockIdx.x;
    int t = threadIdx.x, wv = t >> 6, lane = t & 63;
    __shared__ int wsum[4];
    __shared__ int base_sh;
    if (t == 0) base_sh = 0;
    __syncthreads();
    for (int e = 0; e < 8; e++) {
        int r0 = b * 1024 + t * 4;
        int f[4], c = 0;
        #pragma unroll
        for (int i = 0; i < 4; i++) {
            f[i] = (rw[(long)(r0 + i) * 8 + e] != 0.f) ? 1 : 0;
            c += f[i];
        }
        int incl = c;
        #pragma unroll
        for (int o = 1; o < 64; o <<= 1) {
            int n = __shfl_up(incl, o, 64);
            if (lane >= o) incl += n;
        }
        if (lane == 63) wsum[wv] = incl;
        __syncthreads();
        int woff = 0;
        #pragma unroll
        for (int k = 0; k < 4; k++) if (k < wv) woff += wsum[k];
        int tot = wsum[0] + wsum[1] + wsum[2] + wsum[3];
        int excl = incl - c + woff;
        int base = base_sh;
        int slot = excl;
        #pragma unroll
        for (int i = 0; i < 4; i++) {
            int r = r0 + i;
            if (f[i]) {
                int ps = base + slot;
                prix[b * 3072 + ps] = r;
                act[b * 3072 + ps] = 1;
                smap[(long)r * 8 + e] = ps;
                slot++;
            } else {
                smap[(long)r * 8 + e] = -1;
            }
        }
        int pad = (tot + 127) & ~127;
        for (int s = tot + t; s < pad; s += 256) {
            prix[b * 3072 + base + s] = b * 1024;
            act[b * 3072 + base + s] = 0;
        }
        for (int k = t; k < (pad >> 7); k += 256)
            tmap[b * 32 + (base >> 7) + k] = e;
        __syncthreads();
        if (t == 0) base_sh = base + pad;
        __syncthreads();
    }
    if (t == 0) {
        tt[b] = base_sh >> 7;
        pt[b] = base_sh;
    }
}

// ---------------- merged dense GEMM: z=0..7 -> K (normal C), z=8..15 -> V (transposed C) ----------------
__global__ __launch_bounds__(256)
void gemm_kv_kernel(const u16* __restrict__ A,
                    const u16* __restrict__ Wkv,
                    u16* __restrict__ CK, u16* __restrict__ CV,
                    const float* __restrict__ biasKV) {
    __shared__ __align__(16) u16 As[2][128 * 64];
    __shared__ __align__(16) u16 Bs[2][128 * 64];
    const int z = blockIdx.z;
    const u16* Bb = Wkv + (long)z * 262144 + (long)blockIdx.x * 128 * 512;

    const int tid = threadIdx.x;
    const int w = tid >> 6, lane = tid & 63;
    const int wy = w >> 1, wx = w & 1;
    const int quad = lane >> 4, mrow = lane & 15;

    long arow[4];
    #pragma unroll
    for (int j = 0; j < 4; ++j) arow[j] = (long)blockIdx.y * 128 + ((j * 256 + tid) >> 3);

    floatx4 acc[4][4];
    #pragma unroll
    for (int i = 0; i < 4; i++)
        #pragma unroll
        for (int j = 0; j < 4; j++)
            acc[i][j] = floatx4{0.f, 0.f, 0.f, 0.f};

    stage64(A, 512, arow, Bb, 512, 0, tid, As[0], Bs[0]);
    for (int it = 0; it < 8; ++it) {
        const int cur = it & 1;
        __syncthreads();
        if (it + 1 < 8)
            stage64(A, 512, arow, Bb, 512, (it + 1) << 6, tid, As[1 - cur], Bs[1 - cur]);
        compute64(As[cur], Bs[cur], wy, wx, quad, mrow, acc);
    }

    const float* biasb = biasKV + (long)z * 512 + blockIdx.x * 128;
    if (z >= 8) {   // V: transposed C into VT layout
        u16* Cb = CV + (long)(z - 8) * 2097152;
        #pragma unroll
        for (int ni = 0; ni < 4; ni++) {
            const int colt = wx * 64 + ni * 16 + mrow;
            const int n = blockIdx.x * 128 + colt;
            float bv = biasb[colt];
            #pragma unroll
            for (int mi = 0; mi < 4; mi++) {
                #pragma unroll
                for (int r = 0; r < 4; r++) {
                    const int m = blockIdx.y * 128 + wy * 64 + mi * 16 + quad * 4 + r;
                    float v = acc[mi][ni][r] + bv;
                    long addr = ((long)(((m >> 10) << 2) + (n >> 7)) * 128 + (n & 127)) * 1024 + (m & 1023);
                    Cb[addr] = f2bf_bits(v);
                }
            }
        }
    } else {        // K: normal row-major C
        u16* Cb = CK + (long)z * 2097152 + (long)blockIdx.y * 128 * 512 + blockIdx.x * 128;
        #pragma unroll
        for (int ni = 0; ni < 4; ni++) {
            const int col = wx * 64 + ni * 16 + mrow;
            float bv = biasb[col];
            #pragma unroll
            for (int mi = 0; mi < 4; mi++) {
                #pragma unroll
                for (int r = 0; r < 4; r++) {
                    const int row = wy * 64 + mi * 16 + quad * 4 + r;
                    Cb[(long)row * 512 + col] = f2bf_bits(acc[mi][ni][r] + bv);
                }
            }
        }
    }
}

// ---------------- Qp packed-gather GEMM (separate launch: keeps kv kernel at 88 VGPR) ----------------
// grid x=4, y=96 (b = y/24, tile = y%24)
__global__ __launch_bounds__(256)
void gemm_qp_kernel(const u16* __restrict__ XB, const u16* __restrict__ Wq,
                    u16* __restrict__ QP, const float* __restrict__ biasQ,
                    const int* __restrict__ tmap, const int* __restrict__ tt,
                    const int* __restrict__ prix) {
    const int b = blockIdx.y / 24, tile = blockIdx.y % 24;
    if (tile >= tt[b]) return;
    const int e = tmap[b * 32 + tile];
    __shared__ __align__(16) u16 As[2][128 * 64];
    __shared__ __align__(16) u16 Bs[2][128 * 64];
    const long rbase = (long)b * 3072 + tile * 128;
    const u16* Bb = Wq + (long)e * 262144 + (long)blockIdx.x * 128 * 512;

    const int tid = threadIdx.x;
    const int w = tid >> 6, lane = tid & 63;
    const int wy = w >> 1, wx = w & 1;
    const int quad = lane >> 4, mrow = lane & 15;

    long arow[4];
    #pragma unroll
    for (int j = 0; j < 4; ++j)
        arow[j] = (long)prix[b * 3072 + tile * 128 + ((j * 256 + tid) >> 3)];

    floatx4 acc[4][4];
    #pragma unroll
    for (int i = 0; i < 4; i++)
        #pragma unroll
        for (int j = 0; j < 4; j++)
            acc[i][j] = floatx4{0.f, 0.f, 0.f, 0.f};

    stage64(XB, 512, arow, Bb, 512, 0, tid, As[0], Bs[0]);
    for (int it = 0; it < 8; ++it) {
        const int cur = it & 1;
        __syncthreads();
        if (it + 1 < 8)
            stage64(XB, 512, arow, Bb, 512, (it + 1) << 6, tid, As[1 - cur], Bs[1 - cur]);
        compute64(As[cur], Bs[cur], wy, wx, quad, mrow, acc);
    }

    u16* Cb = QP + rbase * 512 + blockIdx.x * 128;
    const float* biasb = biasQ + blockIdx.x * 128;
    #pragma unroll
    for (int ni = 0; ni < 4; ni++) {
        const int col = wx * 64 + ni * 16 + mrow;
        float bv = biasb[col];
        #pragma unroll
        for (int mi = 0; mi < 4; mi++) {
            #pragma unroll
            for (int r = 0; r < 4; r++) {
                const int row = wy * 64 + mi * 16 + quad * 4 + r;
                Cb[(long)row * 512 + col] = f2bf_bits(acc[mi][ni][r] + bv);
            }
        }
    }
}

// ---------------- fused attention: S^T = K@Q^T -> exp -> P@V, no S round trip (R2-proven) ----------------
// grid x=24 (packed tiles), y=16 (b*4+h). OC block-exclusively aliases QP (read-before-write).
__global__ __launch_bounds__(256, 2)
void attn_fused_kernel(const u16* __restrict__ QP, const u16* __restrict__ Km,
                       const u16* __restrict__ VT, u16* __restrict__ OC,
                       const int* __restrict__ tmap, const int* __restrict__ tt, float alpha) {
    const int tile = blockIdx.x;
    const int bh = blockIdx.y;
    const int b = bh >> 2, h = bh & 3;
    if (tile >= tt[b]) return;
    const int e = tmap[b * 32 + tile];

    __shared__ __align__(16) u16 Bs[2][128 * 64];   // K-tile, then V-tile
    __shared__ __align__(16) u16 Ps[2][128 * 64];   // Q staging, then P (B-operand layout)
    __shared__ float rs_sh[2][128];

    const int tid = threadIdx.x;
    const int w = tid >> 6, lane = tid & 63;
    const int wy = w >> 1, wx = w & 1;
    const int quad = lane >> 4, mrow = lane & 15;

    const u16* Qbase = QP + ((long)b * 3072 + tile * 128) * 512 + h * 128;
    const u16* Kbase = Km + ((long)e * 4096 + b * 1024) * 512 + h * 128;
    const u16* Vbase = VT + ((long)e * 16 + bh) * 131072;

    // prologue: stage Q into Ps, then pull fragments into registers
    stage_one(Qbase, 512, tid, Ps[0]);
    stage_one(Qbase + 64, 512, tid, Ps[1]);
    __syncthreads();
    bfv8 qf[2][2][4];
    #pragma unroll
    for (int c = 0; c < 2; c++)
        #pragma unroll
        for (int kk = 0; kk < 2; kk++)
            #pragma unroll
            for (int ni = 0; ni < 4; ni++) {
                const int r = wx * 64 + ni * 16 + mrow;
                const int slot = (kk * 4 + quad) ^ (r & 7);
                qf[c][kk][ni] = *(const bfv8*)&Ps[c][r * 64 + slot * 8];
            }

    floatx4 acc_o[4][4];
    float rsum[4];
    #pragma unroll
    for (int i = 0; i < 4; i++) {
        rsum[i] = 0.f;
        #pragma unroll
        for (int j = 0; j < 4; j++) acc_o[i][j] = floatx4{0.f, 0.f, 0.f, 0.f};
    }

    for (int kt = 0; kt < 8; ++kt) {
        __syncthreads();                       // Bs + Ps free (prev PV reads done; kt=0: qf loaded)
        stage_one(Kbase + (long)kt * 128 * 512,      512, tid, Bs[0]);
        stage_one(Kbase + (long)kt * 128 * 512 + 64, 512, tid, Bs[1]);
        __syncthreads();                       // K ready

        floatx4 acc_s[4][4];
        #pragma unroll
        for (int i = 0; i < 4; i++)
            #pragma unroll
            for (int j = 0; j < 4; j++) acc_s[i][j] = floatx4{0.f, 0.f, 0.f, 0.f};
        computeQK(Bs[0], qf[0], wy, quad, mrow, acc_s);
        computeQK(Bs[1], qf[1], wy, quad, mrow, acc_s);

        // p = exp(alpha*s); per-lane row sums (cols = queries are lane-local in S^T layout)
        #pragma unroll
        for (int mi = 0; mi < 4; mi++)
            #pragma unroll
            for (int ni = 0; ni < 4; ni++)
                #pragma unroll
                for (int r = 0; r < 4; r++) {
                    float p = __expf(acc_s[mi][ni][r] * alpha);
                    acc_s[mi][ni][r] = p;
                    rsum[ni] += p;
                }

        __syncthreads();                       // all QK reads of Bs done
        stage_one(Vbase + kt * 128,      1024, tid, Bs[0]);
        stage_one(Vbase + kt * 128 + 64, 1024, tid, Bs[1]);
        // write P into Ps as B-operand [query][key-chunk], chunk = wy; packed b32 pairs
        u16* Pw = Ps[wy];
        #pragma unroll
        for (int mi = 0; mi < 4; mi++) {
            const int sb = mi * 2 + (quad >> 1);
            #pragma unroll
            for (int ni = 0; ni < 4; ni++) {
                const int q = wx * 64 + ni * 16 + mrow;
                u16* pr = Pw + q * 64 + (sb ^ (q & 7)) * 8 + (quad & 1) * 4;
                #pragma unroll
                for (int r = 0; r < 4; r += 2) {
                    uint32_t pk = (uint32_t)f2bf_bits(acc_s[mi][ni][r]) |
                                  ((uint32_t)f2bf_bits(acc_s[mi][ni][r + 1]) << 16);
                    *(uint32_t*)(pr + r) = pk;
                }
            }
        }
        __syncthreads();                       // V + P ready
        compute64(Bs[0], Ps[0], wy, wx, quad, mrow, acc_o);   // O^T += V^T @ P^T
        compute64(Bs[1], Ps[1], wy, wx, quad, mrow, acc_o);
    }

    // row sums: reduce over quad lanes, then across wy waves via LDS
    #pragma unroll
    for (int ni = 0; ni < 4; ni++) {
        float v = rsum[ni];
        v += __shfl_xor(v, 16, 64);
        v += __shfl_xor(v, 32, 64);
        if (quad == 0) rs_sh[wy][wx * 64 + ni * 16 + mrow] = v;
    }
    __syncthreads();
    u16* Cb = OC + ((long)b * 3072 + tile * 128) * 512 + h * 128;
    #pragma unroll
    for (int ni = 0; ni < 4; ni++) {
        const int q = wx * 64 + ni * 16 + mrow;
        const float inv = 1.f / (rs_sh[0][q] + rs_sh[1][q]);
        #pragma unroll
        for (int mi = 0; mi < 4; mi++) {
            ushort4 st;
            st.x = f2bf_bits(acc_o[mi][ni][0] * inv);
            st.y = f2bf_bits(acc_o[mi][ni][1] * inv);
            st.z = f2bf_bits(acc_o[mi][ni][2] * inv);
            st.w = f2bf_bits(acc_o[mi][ni][3] * inv);
            *(ushort4*)(Cb + (long)q * 512 + wy * 64 + mi * 16 + quad * 4) = st;
        }
    }
}

// ---------------- packed GEMM (Wo / FFN1): per-tile expert weights ----------------
// grid x = N/128, y = 96 (b = y/24, tile = y%24)
template<bool RELU>
__global__ __launch_bounds__(256)
void gemm_packed_kernel(const u16* __restrict__ A, int lda,
                        const u16* __restrict__ B, int ldb, long sBe,
                        u16* __restrict__ C, int ldc,
                        const float* __restrict__ bias, long sBiasE,
                        const int* __restrict__ tmap, const int* __restrict__ tt, int K) {
    const int b = blockIdx.y / 24, tile = blockIdx.y % 24;
    if (tile >= tt[b]) return;
    const int e = tmap[b * 32 + tile];
    __shared__ __align__(16) u16 As[2][128 * 64];
    __shared__ __align__(16) u16 Bs[2][128 * 64];
    const long rbase = (long)b * 3072 + tile * 128;
    const u16* Ab = A + rbase * lda;
    const u16* Bb = B + (long)e * sBe + (long)blockIdx.x * 128 * ldb;

    const int tid = threadIdx.x;
    const int w = tid >> 6, lane = tid & 63;
    const int wy = w >> 1, wx = w & 1;
    const int quad = lane >> 4, mrow = lane & 15;

    long arow[4];
    #pragma unroll
    for (int j = 0; j < 4; ++j) arow[j] = (j * 256 + tid) >> 3;

    floatx4 acc[4][4];
    #pragma unroll
    for (int i = 0; i < 4; i++)
        #pragma unroll
        for (int j = 0; j < 4; j++)
            acc[i][j] = floatx4{0.f, 0.f, 0.f, 0.f};

    const int nk = K >> 6;
    stage64(Ab, lda, arow, Bb, ldb, 0, tid, As[0], Bs[0]);
    for (int it = 0; it < nk; ++it) {
        const int cur = it & 1;
        __syncthreads();
        if (it + 1 < nk)
            stage64(Ab, lda, arow, Bb, ldb, (it + 1) << 6, tid, As[1 - cur], Bs[1 - cur]);
        compute64(As[cur], Bs[cur], wy, wx, quad, mrow, acc);
    }

    u16* Cb = C + rbase * ldc + (long)blockIdx.x * 128;
    const float* biasb = bias + (long)e * sBiasE + blockIdx.x * 128;
    #pragma unroll
    for (int ni = 0; ni < 4; ni++) {
        const int col = wx * 64 + ni * 16 + mrow;
        float bv = biasb[col];
        #pragma unroll
        for (int mi = 0; mi < 4; mi++) {
            #pragma unroll
            for (int r = 0; r < 4; r++) {
                const int row = wy * 64 + mi * 16 + quad * 4 + r;
                float v = acc[mi][ni][r] + bv;
                if (RELU) v = fmaxf(v, 0.f);
                Cb[(long)row * ldc + col] = f2bf_bits(v);
            }
        }
    }
}

// ---------------- FFN2 K-split: z=0 keys [0,1024), z=1 [1024,2048); f32 partials, no bias ----------------
// grid (4, 96, 2)
__global__ __launch_bounds__(256)
void gemm_ffn2_half_kernel(const u16* __restrict__ MID, const u16* __restrict__ W2T,
                           float* __restrict__ P0, float* __restrict__ P1,
                           const int* __restrict__ tmap, const int* __restrict__ tt) {
    const int b = blockIdx.y / 24, tile = blockIdx.y % 24;
    if (tile >= tt[b]) return;
    const int e = tmap[b * 32 + tile];
    __shared__ __align__(16) u16 As[2][128 * 64];
    __shared__ __align__(16) u16 Bs[2][128 * 64];
    const long rbase = (long)b * 3072 + tile * 128;
    const int koff = blockIdx.z * 1024;
    const u16* Ab = MID + rbase * 2048 + koff;
    const u16* Bb = W2T + (long)e * 1048576 + (long)blockIdx.x * 128 * 2048 + koff;

    const int tid = threadIdx.x;
    const int w = tid >> 6, lane = tid & 63;
    const int wy = w >> 1, wx = w & 1;
    const int quad = lane >> 4, mrow = lane & 15;

    long arow[4];
    #pragma unroll
    for (int j = 0; j < 4; ++j) arow[j] = (j * 256 + tid) >> 3;

    floatx4 acc[4][4];
    #pragma unroll
    for (int i = 0; i < 4; i++)
        #pragma unroll
        for (int j = 0; j < 4; j++)
            acc[i][j] = floatx4{0.f, 0.f, 0.f, 0.f};

    stage64(Ab, 2048, arow, Bb, 2048, 0, tid, As[0], Bs[0]);
    for (int it = 0; it < 16; ++it) {
        const int cur = it & 1;
        __syncthreads();
        if (it + 1 < 16)
            stage64(Ab, 2048, arow, Bb, 2048, (it + 1) << 6, tid, As[1 - cur], Bs[1 - cur]);
        compute64(As[cur], Bs[cur], wy, wx, quad, mrow, acc);
    }

    float* Cb = (blockIdx.z ? P1 : P0) + rbase * 512 + (long)blockIdx.x * 128;
    #pragma unroll
    for (int ni = 0; ni < 4; ni++) {
        const int col = wx * 64 + ni * 16 + mrow;
        #pragma unroll
        for (int mi = 0; mi < 4; mi++) {
            #pragma unroll
            for (int r = 0; r < 4; r++) {
                const int row = wy * 64 + mi * 16 + quad * 4 + r;
                Cb[(long)row * 512 + col] = acc[mi][ni][r];
            }
        }
    }
}

// ---------------- LN1 on packed rows ----------------
__global__ __launch_bounds__(128)
void ln1_kernel(const float* __restrict__ x, const u16* __restrict__ tc,
                const int* __restrict__ prix, const int* __restrict__ act,
                const int* __restrict__ tmap, const int* __restrict__ pt,
                const float* __restrict__ s_all, const float* __restrict__ b_all,
                u16* __restrict__ hb) {
    int blk = blockIdx.x;
    int b = blk / 3072, pslot = blk % 3072;
    if (pslot >= pt[b]) return;
    long row = (long)b * 3072 + pslot;
    int tid = threadIdx.x, w = tid >> 6, lane = tid & 63;
    if (!act[row]) {
        *(ushort4*)(hb + row * 512 + tid * 4) = make_ushort4(0, 0, 0, 0);
        return;
    }
    int r = prix[row];
    int e = tmap[b * 32 + (pslot >> 7)];
    float4 xv = *(const float4*)(x + (long)r * 512 + tid * 4);
    ushort4 tu = *(const ushort4*)(tc + row * 512 + tid * 4);
    float v[4] = {xv.x + bf_bits2f(tu.x), xv.y + bf_bits2f(tu.y),
                  xv.z + bf_bits2f(tu.z), xv.w + bf_bits2f(tu.w)};
    float sum = v[0] + v[1] + v[2] + v[3];
    #pragma unroll
    for (int o = 32; o; o >>= 1) sum += __shfl_down(sum, o, 64);
    __shared__ float sh[4];
    if (lane == 0) sh[w] = sum;
    __syncthreads();
    float mu = (sh[0] + sh[1]) * (1.f / 512.f);
    float sq = 0.f;
    #pragma unroll
    for (int j = 0; j < 4; j++) { float d = v[j] - mu; sq += d * d; }
    #pragma unroll
    for (int o = 32; o; o >>= 1) sq += __shfl_down(sq, o, 64);
    if (lane == 0) sh[2 + w] = sq;
    __syncthreads();
    float inv = 1.f / sqrtf((sh[2] + sh[3]) * (1.f / 512.f) + 1e-5f);
    float4 sv = *(const float4*)(s_all + e * 512 + tid * 4);
    float4 bv = *(const float4*)(b_all + e * 512 + tid * 4);
    ushort4 ub;
    ub.x = f2bf_bits((v[0] - mu) * inv * sv.x + bv.x);
    ub.y = f2bf_bits((v[1] - mu) * inv * sv.y + bv.y);
    ub.z = f2bf_bits((v[2] - mu) * inv * sv.z + bv.z);
    ub.w = f2bf_bits((v[3] - mu) * inv * sv.w + bv.w);
    *(ushort4*)(hb + row * 512 + tid * 4) = ub;
}

// ---------------- LN2 + FFN2 partial-sum + bias + weighted accumulate over all 8 experts ----------------
__global__ __launch_bounds__(128)
void ln2acc_kernel(const u16* __restrict__ hb, const float* __restrict__ p0,
                   const float* __restrict__ p1, const float* __restrict__ b2,
                   const float* __restrict__ s_all, const float* __restrict__ b_all,
                   const float* __restrict__ rw, const int* __restrict__ smap,
                   float* __restrict__ out) {
    long r = blockIdx.x;
    int b = (int)(r >> 10);
    int tid = threadIdx.x, w = tid >> 6, lane = tid & 63;
    __shared__ float sh[4];
    float4 acc = make_float4(0.f, 0.f, 0.f, 0.f);
    for (int e = 0; e < 8; e++) {
        int ps = smap[r * 8 + e];
        if (ps >= 0) {   // block-uniform
            float wgt = rw[r * 8 + e];
            long row = (long)b * 3072 + ps;
            ushort4 hu = *(const ushort4*)(hb + row * 512 + tid * 4);
            float4 f0 = *(const float4*)(p0 + row * 512 + tid * 4);
            float4 f1 = *(const float4*)(p1 + row * 512 + tid * 4);
            float4 bb = *(const float4*)(b2 + (long)e * 512 + tid * 4);
            float v[4] = {bf_bits2f(hu.x) + f0.x + f1.x + bb.x,
                          bf_bits2f(hu.y) + f0.y + f1.y + bb.y,
                          bf_bits2f(hu.z) + f0.z + f1.z + bb.z,
                          bf_bits2f(hu.w) + f0.w + f1.w + bb.w};
            float sum = v[0] + v[1] + v[2] + v[3];
            #pragma unroll
            for (int o = 32; o; o >>= 1) sum += __shfl_down(sum, o, 64);
            if (lane == 0) sh[w] = sum;
            __syncthreads();
            float mu = (sh[0] + sh[1]) * (1.f / 512.f);
            float sq = 0.f;
            #pragma unroll
            for (int j = 0; j < 4; j++) { float d = v[j] - mu; sq += d * d; }
            #pragma unroll
            for (int o = 32; o; o >>= 1) sq += __shfl_down(sq, o, 64);
            if (lane == 0) sh[2 + w] = sq;
            __syncthreads();
            float inv = 1.f / sqrtf((sh[2] + sh[3]) * (1.f / 512.f) + 1e-5f);
            float4 sv = *(const float4*)(s_all + e * 512 + tid * 4);
            float4 bv = *(const float4*)(b_all + e * 512 + tid * 4);
            acc.x += wgt * ((v[0] - mu) * inv * sv.x + bv.x);
            acc.y += wgt * ((v[1] - mu) * inv * sv.y + bv.y);
            acc.z += wgt * ((v[2] - mu) * inv * sv.z + bv.z);
            acc.w += wgt * ((v[3] - mu) * inv * sv.w + bv.w);
            __syncthreads();
        }
    }
    *(float4*)(out + r * 512 + tid * 4) = acc;
}

// ---------------- workspace layout (bytes), ws_size = 256 MiB ----------------
static const size_t WB_B   = 0;           // 48 MiB: wq,wk,wv,wo (8x262144 each), w1 (8x1048576), w2 (8x1048576)
static const size_t RW_B   = 50331648;    // f32 [4096][8]
static const size_t PB_B   = 50462720;    // f32 [3][8][512]
static const size_t TT_B   = 50511872;    // i32[4] tiles per b
static const size_t PT_B   = 50511888;    // i32[4] packed rows per b
static const size_t TMAP_B = 50511904;    // i32 [4][32]
static const size_t PRIX_B = 50512416;    // i32 [4][3072]
static const size_t ACT_B  = 50561568;    // i32 [4][3072]
static const size_t SMAP_B = 50610720;    // i32 [4096][8]
static const size_t XB_B   = 50741792;    // bf16 [4096][512]
static const size_t Q8_B   = 54936096;    // bf16 packed Q [4][3072][512] (12.6 MiB)
static const size_t K8_B   = 88490528;    // bf16 [8][4096][512] (32 MiB)
static const size_t VT_B   = 122044960;   // bf16 [8][16][128][1024] (32 MiB)
static const size_t S_B    = 155599392;   // scratch: FFN mid bf16 [4][3072][2048] (50.3 MiB)
static const size_t OC_B   = Q8_B;        // fused attn out: block-exclusive alias of QP
static const size_t TC_B   = K8_B;        // bf16 [4][3072][512] — K dead after attn
static const size_t HB_B   = Q8_B;        // LN1 out — OC dead after Wo
static const size_t MID_B  = S_B;         // ends at 205,931,040
static const size_t FP0_B  = VT_B;        // f32 [4][3072][512] = 25.2 MiB — VT dead after attn
static const size_t FP1_B  = 205931040;   // f32 [4][3072][512], ends 231,096,864 < 268,435,456

extern "C" void kernel_launch(void* const* d_in, const int* in_sizes, int n_in,
                              void* d_out, int out_size, void* d_ws, size_t ws_size,
                              hipStream_t stream) {
    const float* x      = (const float*)d_in[0];
    const float* gate_w = (const float*)d_in[1];
    const float* gate_b = (const float*)d_in[2];
    const float* ln1_s  = (const float*)d_in[3];
    const float* ln1_b  = (const float*)d_in[4];
    const float* ln2_s  = (const float*)d_in[5];
    const float* ln2_b  = (const float*)d_in[6];
    const float* wq = (const float*)d_in[7];
    const float* wk = (const float*)d_in[8];
    const float* wv = (const float*)d_in[9];
    const float* wo = (const float*)d_in[10];
    const float* bo = (const float*)d_in[14];
    const float* w1 = (const float*)d_in[15];
    const float* b1 = (const float*)d_in[16];
    const float* w2 = (const float*)d_in[17];
    const float* b2 = (const float*)d_in[18];
    float* out = (float*)d_out;

    char* ws = (char*)d_ws;
    u16*   WB   = (u16*)(ws + WB_B);
    float* RW   = (float*)(ws + RW_B);
    float* PB   = (float*)(ws + PB_B);
    int*   TT   = (int*)(ws + TT_B);
    int*   PT   = (int*)(ws + PT_B);
    int*   TMAP = (int*)(ws + TMAP_B);
    int*   PRIX = (int*)(ws + PRIX_B);
    int*   ACT  = (int*)(ws + ACT_B);
    int*   SMAP = (int*)(ws + SMAP_B);
    u16*   XB   = (u16*)(ws + XB_B);
    u16*   QP   = (u16*)(ws + Q8_B);
    u16*   K8   = (u16*)(ws + K8_B);
    u16*   VT8  = (u16*)(ws + VT_B);
    u16*   OC   = (u16*)(ws + OC_B);
    u16*   TC   = (u16*)(ws + TC_B);
    u16*   HB   = (u16*)(ws + HB_B);
    u16*   MID  = (u16*)(ws + MID_B);
    float* FP0  = (float*)(ws + FP0_B);
    float* FP1  = (float*)(ws + FP1_B);

    // ---- setup ----
    cast_bf16_kernel<<<dim3(2096), 256, 0, stream>>>(x, XB, 4096 * 512 / 4,
                                                     (const float*)d_in[11], (const float*)d_in[12],
                                                     (const float*)d_in[13], PB);
    transpose_all_kernel<<<dim3(24576), dim3(32,8), 0, stream>>>(wq, wk, wv, wo, w1, w2, WB);
    router_kernel<<<4096, 512, 0, stream>>>(x, gate_w, gate_b, RW, out + 2097152);
    build_lists_kernel<<<4, 256, 0, stream>>>(RW, PRIX, ACT, SMAP, TMAP, TT, PT);

    const float isq = 0.08838834764831845f;  // 1/sqrt(128)

    // ---- K + V for all 8 experts in one launch (z<8: K normal, z>=8: V transposed) ----
    gemm_kv_kernel<<<dim3(4,32,16), 256, 0, stream>>>(XB, WB + 2097152, K8, VT8, PB + 4096);
    // ---- Q only for packed (routed) rows, gathered from x (separate launch: 88-VGPR kv kernel) ----
    gemm_qp_kernel<<<dim3(4,96), 256, 0, stream>>>(XB, WB, QP, PB, TMAP, TT, PRIX);

    // ---- fused attention (R2-proven structure, 8 x 128-key steps) ----
    attn_fused_kernel<<<dim3(24, 16), 256, 0, stream>>>(QP, K8, VT8, OC, TMAP, TT, isq);

    // ---- Wo ----
    gemm_packed_kernel<false><<<dim3(4,96), 256, 0, stream>>>(
        OC, 512, WB + 6291456, 512, 262144, TC, 512, bo, 512, TMAP, TT, 512);
    // ---- LN1 ----
    ln1_kernel<<<12288, 128, 0, stream>>>(x, TC, PRIX, ACT, TMAP, PT, ln1_s, ln1_b, HB);
    // ---- FFN1 ----
    gemm_packed_kernel<true><<<dim3(16,96), 256, 0, stream>>>(
        HB, 512, WB + 8388608, 512, 1048576, MID, 2048, b1, 2048, TMAP, TT, 512);
    // ---- FFN2, K-split halves into f32 partials (2x occupancy) ----
    gemm_ffn2_half_kernel<<<dim3(4,96,2), 256, 0, stream>>>(
        MID, WB + 16777216, FP0, FP1, TMAP, TT);
    // ---- LN2 + partial-sum + bias + routing-weighted accumulate ----
    ln2acc_kernel<<<4096, 128, 0, stream>>>(HB, FP0, FP1, b2, ln2_s, ln2_b, RW, SMAP, out);
}

// Round 10
// 418.399 us; speedup vs baseline: 1.0726x; 1.0029x over previous
//
#include <hip/hip_runtime.h>
#include <hip/hip_bf16.h>
#include <stdint.h>

using u16 = unsigned short;
typedef float floatx4 __attribute__((ext_vector_type(4)));
typedef __bf16 bfv8 __attribute__((ext_vector_type(8)));

#define AS1 __attribute__((address_space(1)))
#define AS3 __attribute__((address_space(3)))

__device__ __forceinline__ u16 f2bf_bits(float f) {
    __hip_bfloat16 h = __float2bfloat16(f);
    u16 u;
    __builtin_memcpy(&u, &h, 2);
    return u;
}
__device__ __forceinline__ float bf_bits2f(u16 u) {
    __hip_bfloat16 h;
    __builtin_memcpy(&h, &u, 2);
    return __bfloat162float(h);
}
__device__ __forceinline__ void gload_lds16(const void* g, void* l) {
    __builtin_amdgcn_global_load_lds((AS1 void*)(uintptr_t)g, (AS3 void*)l, 16, 0, 0);
}

// ---- BK=64 tile staging (dbuf), XOR-swizzled chunks ----
__device__ __forceinline__ void stage64(const u16* __restrict__ Abase, long lda, const long* arow,
                                        const u16* __restrict__ Bb, long ldb, int k0, int tid,
                                        u16* Ad, u16* Bd) {
    #pragma unroll
    for (int j = 0; j < 4; ++j) {
        const int q   = j * 256 + tid;
        const int row = q >> 3;
        const int cg  = (q & 7) ^ (row & 7);
        gload_lds16(Abase + arow[j] * lda + k0 + cg * 8, Ad + q * 8);
        gload_lds16(Bb + (long)row * ldb + k0 + cg * 8, Bd + q * 8);
    }
}
// stage a single 128x64 chunk (contiguous rows)
__device__ __forceinline__ void stage_one(const u16* __restrict__ base, long ld, int tid, u16* dst) {
    #pragma unroll
    for (int j = 0; j < 4; ++j) {
        const int q   = j * 256 + tid;
        const int row = q >> 3;
        const int cg  = (q & 7) ^ (row & 7);
        gload_lds16(base + (long)row * ld + cg * 8, dst + q * 8);
    }
}
__device__ __forceinline__ void compute64(const u16* Ab, const u16* Bb, int wy, int wx,
                                          int quad, int mrow, floatx4 acc[4][4]) {
    #pragma unroll
    for (int kk = 0; kk < 2; ++kk) {
        bfv8 af[4], bf[4];
        #pragma unroll
        for (int mi = 0; mi < 4; mi++) {
            const int r = wy * 64 + mi * 16 + mrow;
            const int slot = (kk * 4 + quad) ^ (r & 7);
            af[mi] = *(const bfv8*)&Ab[r * 64 + slot * 8];
        }
        #pragma unroll
        for (int ni = 0; ni < 4; ni++) {
            const int r = wx * 64 + ni * 16 + mrow;
            const int slot = (kk * 4 + quad) ^ (r & 7);
            bf[ni] = *(const bfv8*)&Bb[r * 64 + slot * 8];
        }
        #pragma unroll
        for (int mi = 0; mi < 4; mi++)
            #pragma unroll
            for (int ni = 0; ni < 4; ni++)
                acc[mi][ni] = __builtin_amdgcn_mfma_f32_16x16x32_bf16(af[mi], bf[ni], acc[mi][ni], 0, 0, 0);
    }
}
// A from LDS (K-tile rows=keys), B from registers (Q fragments)
__device__ __forceinline__ void computeQK(const u16* Kb, const bfv8 qf[2][4], int wy,
                                          int quad, int mrow, floatx4 acc[4][4]) {
    #pragma unroll
    for (int kk = 0; kk < 2; ++kk) {
        bfv8 af[4];
        #pragma unroll
        for (int mi = 0; mi < 4; mi++) {
            const int r = wy * 64 + mi * 16 + mrow;
            const int slot = (kk * 4 + quad) ^ (r & 7);
            af[mi] = *(const bfv8*)&Kb[r * 64 + slot * 8];
        }
        #pragma unroll
        for (int mi = 0; mi < 4; mi++)
            #pragma unroll
            for (int ni = 0; ni < 4; ni++)
                acc[mi][ni] = __builtin_amdgcn_mfma_f32_16x16x32_bf16(af[mi], qf[kk][ni], acc[mi][ni], 0, 0, 0);
    }
}

// ---------------- merged transpose+cast: wq,wk,wv,wo + w1 + w2, one launch ----------------
// grid 24576 blocks of (32,8): [0,8192) wqkv/wo 512x512, [8192,16384) w1 512x2048, rest w2 2048x512
__global__ void transpose_all_kernel(const float* __restrict__ wq, const float* __restrict__ wk,
                                     const float* __restrict__ wv, const float* __restrict__ wo,
                                     const float* __restrict__ w1, const float* __restrict__ w2,
                                     u16* __restrict__ WB) {
    __shared__ float tile[32][33];
    const int bid = blockIdx.x;
    const float* s; u16* d; int R, C, c0, r0;
    if (bid < 8192) {
        int x = bid & 15, y = (bid >> 4) & 15, z = bid >> 8;
        s = (z < 8 ? wq : z < 16 ? wk : z < 24 ? wv : wo) + (long)(z & 7) * 262144;
        d = WB + (long)z * 262144;
        R = 512; C = 512; c0 = x * 32; r0 = y * 32;
    } else if (bid < 16384) {
        int idx = bid - 8192;
        int x = idx & 63, y = (idx >> 6) & 15, z = idx >> 10;
        s = w1 + (long)z * 1048576;
        d = WB + 8388608 + (long)z * 1048576;
        R = 512; C = 2048; c0 = x * 32; r0 = y * 32;
    } else {
        int idx = bid - 16384;
        int x = idx & 15, y = (idx >> 4) & 63, z = idx >> 10;
        s = w2 + (long)z * 1048576;
        d = WB + 16777216 + (long)z * 1048576;
        R = 2048; C = 512; c0 = x * 32; r0 = y * 32;
    }
    int tx = threadIdx.x, ty = threadIdx.y;
    #pragma unroll
    for (int i = 0; i < 4; i++)
        tile[ty + 8*i][tx] = s[(long)(r0 + ty + 8*i) * C + c0 + tx];
    __syncthreads();
    #pragma unroll
    for (int i = 0; i < 4; i++)
        d[(long)(c0 + ty + 8*i) * R + r0 + tx] = f2bf_bits(tile[tx][ty + 8*i]);
}

// ---------------- merged router + x-cast (+ bias pack in tail blocks) ----------------
// grid 4120 x 512: [0,4096) one row each (router logits/rw + bf16 cast of x row);
// [4096,4120): pack bq/bk/bv -> PB (24 blocks x 512 = 12288)
__global__ __launch_bounds__(512)
void router_cast_kernel(const float* __restrict__ x, const float* __restrict__ gw,
                        const float* __restrict__ gb, float* __restrict__ rw,
                        float* __restrict__ logits_out, u16* __restrict__ xb,
                        const float* __restrict__ bq, const float* __restrict__ bk,
                        const float* __restrict__ bvv, float* __restrict__ pb) {
    if (blockIdx.x >= 4096) {
        int j = (blockIdx.x - 4096) * 512 + threadIdx.x;  // 0..12287
        const float* s = j < 4096 ? bq : (j < 8192 ? bk : bvv);
        pb[j] = s[j & 4095];
        return;
    }
    int row = blockIdx.x;
    int w = threadIdx.x >> 6;
    int lane = threadIdx.x & 63;
    const float* xr = x + (long)row * 512;
    float sum = 0.f;
    #pragma unroll
    for (int i = 0; i < 8; i++) {
        int d = lane + 64 * i;
        float v = xr[d];
        sum += v * gw[d * 8 + w];
        if (i == w) xb[(long)row * 512 + d] = f2bf_bits(v);  // wave w casts chunk w
    }
    #pragma unroll
    for (int o = 32; o; o >>= 1) sum += __shfl_down(sum, o, 64);
    __shared__ float lg[8];
    if (lane == 0) lg[w] = sum + gb[w];
    __syncthreads();
    if (threadIdx.x == 0) {
        float l[8];
        #pragma unroll
        for (int e = 0; e < 8; e++) l[e] = lg[e];
        int i1 = 0;
        for (int e = 1; e < 8; e++) if (l[e] > l[i1]) i1 = e;
        int i2 = -1;
        for (int e = 0; e < 8; e++) { if (e == i1) continue; if (i2 < 0 || l[e] > l[i2]) i2 = e; }
        for (int e = 0; e < 8; e++) {
            float v = (e == i1 || e == i2) ? (l[e] > 0.f ? l[e] : 0.f) : 0.f;
            float r = 0.f, mem = v;
            #pragma unroll
            for (int lvl = 0; lvl < 4; lvl++) {
                float thr = 4.0f / (float)(1 << lvl);
                if (mem >= thr) { r += thr; mem -= thr; }
            }
            rw[(long)row * 8 + e] = r;
            logits_out[(long)row * 8 + e] = l[e];
        }
    }
}

// ---------------- build packed row space: per b, experts packed back-to-back ----------------
__global__ __launch_bounds__(256)
void build_lists_kernel(const float* __restrict__ rw, int* __restrict__ prix,
                        int* __restrict__ act, int* __restrict__ smap,
                        int* __restrict__ tmap, int* __restrict__ tt, int* __restrict__ pt) {
    int b = blockIdx.x;
    int t = threadIdx.x, wv = t >> 6, lane = t & 63;
    __shared__ int wsum[4];
    __shared__ int base_sh;
    if (t == 0) base_sh = 0;
    __syncthreads();
    for (int e = 0; e < 8; e++) {
        int r0 = b * 1024 + t * 4;
        int f[4], c = 0;
        #pragma unroll
        for (int i = 0; i < 4; i++) {
            f[i] = (rw[(long)(r0 + i) * 8 + e] != 0.f) ? 1 : 0;
            c += f[i];
        }
        int incl = c;
        #pragma unroll
        for (int o = 1; o < 64; o <<= 1) {
            int n = __shfl_up(incl, o, 64);
            if (lane >= o) incl += n;
        }
        if (lane == 63) wsum[wv] = incl;
        __syncthreads();
        int woff = 0;
        #pragma unroll
        for (int k = 0; k < 4; k++) if (k < wv) woff += wsum[k];
        int tot = wsum[0] + wsum[1] + wsum[2] + wsum[3];
        int excl = incl - c + woff;
        int base = base_sh;
        int slot = excl;
        #pragma unroll
        for (int i = 0; i < 4; i++) {
            int r = r0 + i;
            if (f[i]) {
                int ps = base + slot;
                prix[b * 3072 + ps] = r;
                act[b * 3072 + ps] = 1;
                smap[(long)r * 8 + e] = ps;
                slot++;
            } else {
                smap[(long)r * 8 + e] = -1;
            }
        }
        int pad = (tot + 127) & ~127;
        for (int s = tot + t; s < pad; s += 256) {
            prix[b * 3072 + base + s] = b * 1024;
            act[b * 3072 + base + s] = 0;
        }
        for (int k = t; k < (pad >> 7); k += 256)
            tmap[b * 32 + (base >> 7) + k] = e;
        __syncthreads();
        if (t == 0) base_sh = base + pad;
        __syncthreads();
    }
    if (t == 0) {
        tt[b] = base_sh >> 7;
        pt[b] = base_sh;
    }
}

// ---------------- merged dense GEMM: z=0..7 -> K (normal C), z=8..15 -> V (transposed C) ----------------
__global__ __launch_bounds__(256)
void gemm_kv_kernel(const u16* __restrict__ A,
                    const u16* __restrict__ Wkv,
                    u16* __restrict__ CK, u16* __restrict__ CV,
                    const float* __restrict__ biasKV) {
    __shared__ __align__(16) u16 As[2][128 * 64];
    __shared__ __align__(16) u16 Bs[2][128 * 64];
    const int z = blockIdx.z;
    const u16* Bb = Wkv + (long)z * 262144 + (long)blockIdx.x * 128 * 512;

    const int tid = threadIdx.x;
    const int w = tid >> 6, lane = tid & 63;
    const int wy = w >> 1, wx = w & 1;
    const int quad = lane >> 4, mrow = lane & 15;

    long arow[4];
    #pragma unroll
    for (int j = 0; j < 4; ++j) arow[j] = (long)blockIdx.y * 128 + ((j * 256 + tid) >> 3);

    floatx4 acc[4][4];
    #pragma unroll
    for (int i = 0; i < 4; i++)
        #pragma unroll
        for (int j = 0; j < 4; j++)
            acc[i][j] = floatx4{0.f, 0.f, 0.f, 0.f};

    stage64(A, 512, arow, Bb, 512, 0, tid, As[0], Bs[0]);
    for (int it = 0; it < 8; ++it) {
        const int cur = it & 1;
        __syncthreads();
        if (it + 1 < 8)
            stage64(A, 512, arow, Bb, 512, (it + 1) << 6, tid, As[1 - cur], Bs[1 - cur]);
        compute64(As[cur], Bs[cur], wy, wx, quad, mrow, acc);
    }

    const float* biasb = biasKV + (long)z * 512 + blockIdx.x * 128;
    if (z >= 8) {   // V: transposed C into VT layout (r=0..3 are addr-consecutive -> ushort4)
        u16* Cb = CV + (long)(z - 8) * 2097152;
        #pragma unroll
        for (int ni = 0; ni < 4; ni++) {
            const int colt = wx * 64 + ni * 16 + mrow;
            const int n = blockIdx.x * 128 + colt;
            float bv = biasb[colt];
            #pragma unroll
            for (int mi = 0; mi < 4; mi++) {
                const int m = blockIdx.y * 128 + wy * 64 + mi * 16 + quad * 4;
                long addr = ((long)(((m >> 10) << 2) + (n >> 7)) * 128 + (n & 127)) * 1024 + (m & 1023);
                ushort4 st;
                st.x = f2bf_bits(acc[mi][ni][0] + bv);
                st.y = f2bf_bits(acc[mi][ni][1] + bv);
                st.z = f2bf_bits(acc[mi][ni][2] + bv);
                st.w = f2bf_bits(acc[mi][ni][3] + bv);
                *(ushort4*)(Cb + addr) = st;
            }
        }
    } else {        // K: normal row-major C
        u16* Cb = CK + (long)z * 2097152 + (long)blockIdx.y * 128 * 512 + blockIdx.x * 128;
        #pragma unroll
        for (int ni = 0; ni < 4; ni++) {
            const int col = wx * 64 + ni * 16 + mrow;
            float bv = biasb[col];
            #pragma unroll
            for (int mi = 0; mi < 4; mi++) {
                #pragma unroll
                for (int r = 0; r < 4; r++) {
                    const int row = wy * 64 + mi * 16 + quad * 4 + r;
                    Cb[(long)row * 512 + col] = f2bf_bits(acc[mi][ni][r] + bv);
                }
            }
        }
    }
}

// ---------------- Qp packed-gather GEMM (separate launch: keeps kv kernel at 88 VGPR) ----------------
// grid x=4, y=96 (b = y/24, tile = y%24)
__global__ __launch_bounds__(256)
void gemm_qp_kernel(const u16* __restrict__ XB, const u16* __restrict__ Wq,
                    u16* __restrict__ QP, const float* __restrict__ biasQ,
                    const int* __restrict__ tmap, const int* __restrict__ tt,
                    const int* __restrict__ prix) {
    const int b = blockIdx.y / 24, tile = blockIdx.y % 24;
    if (tile >= tt[b]) return;
    const int e = tmap[b * 32 + tile];
    __shared__ __align__(16) u16 As[2][128 * 64];
    __shared__ __align__(16) u16 Bs[2][128 * 64];
    const long rbase = (long)b * 3072 + tile * 128;
    const u16* Bb = Wq + (long)e * 262144 + (long)blockIdx.x * 128 * 512;

    const int tid = threadIdx.x;
    const int w = tid >> 6, lane = tid & 63;
    const int wy = w >> 1, wx = w & 1;
    const int quad = lane >> 4, mrow = lane & 15;

    long arow[4];
    #pragma unroll
    for (int j = 0; j < 4; ++j)
        arow[j] = (long)prix[b * 3072 + tile * 128 + ((j * 256 + tid) >> 3)];

    floatx4 acc[4][4];
    #pragma unroll
    for (int i = 0; i < 4; i++)
        #pragma unroll
        for (int j = 0; j < 4; j++)
            acc[i][j] = floatx4{0.f, 0.f, 0.f, 0.f};

    stage64(XB, 512, arow, Bb, 512, 0, tid, As[0], Bs[0]);
    for (int it = 0; it < 8; ++it) {
        const int cur = it & 1;
        __syncthreads();
        if (it + 1 < 8)
            stage64(XB, 512, arow, Bb, 512, (it + 1) << 6, tid, As[1 - cur], Bs[1 - cur]);
        compute64(As[cur], Bs[cur], wy, wx, quad, mrow, acc);
    }

    u16* Cb = QP + rbase * 512 + blockIdx.x * 128;
    const float* biasb = biasQ + blockIdx.x * 128;
    #pragma unroll
    for (int ni = 0; ni < 4; ni++) {
        const int col = wx * 64 + ni * 16 + mrow;
        float bv = biasb[col];
        #pragma unroll
        for (int mi = 0; mi < 4; mi++) {
            #pragma unroll
            for (int r = 0; r < 4; r++) {
                const int row = wy * 64 + mi * 16 + quad * 4 + r;
                Cb[(long)row * 512 + col] = f2bf_bits(acc[mi][ni][r] + bv);
            }
        }
    }
}

// ---------------- fused attention: S^T = K@Q^T -> exp -> P@V, no S round trip (R2-proven) ----------------
// grid x=24 (packed tiles), y=16 (b*4+h). OC block-exclusively aliases QP (read-before-write).
__global__ __launch_bounds__(256, 2)
void attn_fused_kernel(const u16* __restrict__ QP, const u16* __restrict__ Km,
                       const u16* __restrict__ VT, u16* __restrict__ OC,
                       const int* __restrict__ tmap, const int* __restrict__ tt, float alpha) {
    const int tile = blockIdx.x;
    const int bh = blockIdx.y;
    const int b = bh >> 2, h = bh & 3;
    if (tile >= tt[b]) return;
    const int e = tmap[b * 32 + tile];

    __shared__ __align__(16) u16 Bs[2][128 * 64];   // K-tile, then V-tile
    __shared__ __align__(16) u16 Ps[2][128 * 64];   // Q staging, then P (B-operand layout)
    __shared__ float rs_sh[2][128];

    const int tid = threadIdx.x;
    const int w = tid >> 6, lane = tid & 63;
    const int wy = w >> 1, wx = w & 1;
    const int quad = lane >> 4, mrow = lane & 15;

    const u16* Qbase = QP + ((long)b * 3072 + tile * 128) * 512 + h * 128;
    const u16* Kbase = Km + ((long)e * 4096 + b * 1024) * 512 + h * 128;
    const u16* Vbase = VT + ((long)e * 16 + bh) * 131072;

    // prologue: stage Q into Ps, then pull fragments into registers
    stage_one(Qbase, 512, tid, Ps[0]);
    stage_one(Qbase + 64, 512, tid, Ps[1]);
    __syncthreads();
    bfv8 qf[2][2][4];
    #pragma unroll
    for (int c = 0; c < 2; c++)
        #pragma unroll
        for (int kk = 0; kk < 2; kk++)
            #pragma unroll
            for (int ni = 0; ni < 4; ni++) {
                const int r = wx * 64 + ni * 16 + mrow;
                const int slot = (kk * 4 + quad) ^ (r & 7);
                qf[c][kk][ni] = *(const bfv8*)&Ps[c][r * 64 + slot * 8];
            }

    floatx4 acc_o[4][4];
    float rsum[4];
    #pragma unroll
    for (int i = 0; i < 4; i++) {
        rsum[i] = 0.f;
        #pragma unroll
        for (int j = 0; j < 4; j++) acc_o[i][j] = floatx4{0.f, 0.f, 0.f, 0.f};
    }

    for (int kt = 0; kt < 8; ++kt) {
        __syncthreads();                       // Bs + Ps free (prev PV reads done; kt=0: qf loaded)
        stage_one(Kbase + (long)kt * 128 * 512,      512, tid, Bs[0]);
        stage_one(Kbase + (long)kt * 128 * 512 + 64, 512, tid, Bs[1]);
        __syncthreads();                       // K ready

        floatx4 acc_s[4][4];
        #pragma unroll
        for (int i = 0; i < 4; i++)
            #pragma unroll
            for (int j = 0; j < 4; j++) acc_s[i][j] = floatx4{0.f, 0.f, 0.f, 0.f};
        computeQK(Bs[0], qf[0], wy, quad, mrow, acc_s);
        computeQK(Bs[1], qf[1], wy, quad, mrow, acc_s);

        // p = exp(alpha*s); per-lane row sums (cols = queries are lane-local in S^T layout)
        #pragma unroll
        for (int mi = 0; mi < 4; mi++)
            #pragma unroll
            for (int ni = 0; ni < 4; ni++)
                #pragma unroll
                for (int r = 0; r < 4; r++) {
                    float p = __expf(acc_s[mi][ni][r] * alpha);
                    acc_s[mi][ni][r] = p;
                    rsum[ni] += p;
                }

        __syncthreads();                       // all QK reads of Bs done
        stage_one(Vbase + kt * 128,      1024, tid, Bs[0]);
        stage_one(Vbase + kt * 128 + 64, 1024, tid, Bs[1]);
        // write P into Ps as B-operand [query][key-chunk], chunk = wy; packed b32 pairs
        u16* Pw = Ps[wy];
        #pragma unroll
        for (int mi = 0; mi < 4; mi++) {
            const int sb = mi * 2 + (quad >> 1);
            #pragma unroll
            for (int ni = 0; ni < 4; ni++) {
                const int q = wx * 64 + ni * 16 + mrow;
                u16* pr = Pw + q * 64 + (sb ^ (q & 7)) * 8 + (quad & 1) * 4;
                #pragma unroll
                for (int r = 0; r < 4; r += 2) {
                    uint32_t pk = (uint32_t)f2bf_bits(acc_s[mi][ni][r]) |
                                  ((uint32_t)f2bf_bits(acc_s[mi][ni][r + 1]) << 16);
                    *(uint32_t*)(pr + r) = pk;
                }
            }
        }
        __syncthreads();                       // V + P ready
        compute64(Bs[0], Ps[0], wy, wx, quad, mrow, acc_o);   // O^T += V^T @ P^T
        compute64(Bs[1], Ps[1], wy, wx, quad, mrow, acc_o);
    }

    // row sums: reduce over quad lanes, then across wy waves via LDS
    #pragma unroll
    for (int ni = 0; ni < 4; ni++) {
        float v = rsum[ni];
        v += __shfl_xor(v, 16, 64);
        v += __shfl_xor(v, 32, 64);
        if (quad == 0) rs_sh[wy][wx * 64 + ni * 16 + mrow] = v;
    }
    __syncthreads();
    u16* Cb = OC + ((long)b * 3072 + tile * 128) * 512 + h * 128;
    #pragma unroll
    for (int ni = 0; ni < 4; ni++) {
        const int q = wx * 64 + ni * 16 + mrow;
        const float inv = 1.f / (rs_sh[0][q] + rs_sh[1][q]);
        #pragma unroll
        for (int mi = 0; mi < 4; mi++) {
            ushort4 st;
            st.x = f2bf_bits(acc_o[mi][ni][0] * inv);
            st.y = f2bf_bits(acc_o[mi][ni][1] * inv);
            st.z = f2bf_bits(acc_o[mi][ni][2] * inv);
            st.w = f2bf_bits(acc_o[mi][ni][3] * inv);
            *(ushort4*)(Cb + (long)q * 512 + wy * 64 + mi * 16 + quad * 4) = st;
        }
    }
}

// ---------------- packed GEMM (Wo / FFN1): per-tile expert weights ----------------
// grid x = N/128, y = 96 (b = y/24, tile = y%24)
template<bool RELU>
__global__ __launch_bounds__(256)
void gemm_packed_kernel(const u16* __restrict__ A, int lda,
                        const u16* __restrict__ B, int ldb, long sBe,
                        u16* __restrict__ C, int ldc,
                        const float* __restrict__ bias, long sBiasE,
                        const int* __restrict__ tmap, const int* __restrict__ tt, int K) {
    const int b = blockIdx.y / 24, tile = blockIdx.y % 24;
    if (tile >= tt[b]) return;
    const int e = tmap[b * 32 + tile];
    __shared__ __align__(16) u16 As[2][128 * 64];
    __shared__ __align__(16) u16 Bs[2][128 * 64];
    const long rbase = (long)b * 3072 + tile * 128;
    const u16* Ab = A + rbase * lda;
    const u16* Bb = B + (long)e * sBe + (long)blockIdx.x * 128 * ldb;

    const int tid = threadIdx.x;
    const int w = tid >> 6, lane = tid & 63;
    const int wy = w >> 1, wx = w & 1;
    const int quad = lane >> 4, mrow = lane & 15;

    long arow[4];
    #pragma unroll
    for (int j = 0; j < 4; ++j) arow[j] = (j * 256 + tid) >> 3;

    floatx4 acc[4][4];
    #pragma unroll
    for (int i = 0; i < 4; i++)
        #pragma unroll
        for (int j = 0; j < 4; j++)
            acc[i][j] = floatx4{0.f, 0.f, 0.f, 0.f};

    const int nk = K >> 6;
    stage64(Ab, lda, arow, Bb, ldb, 0, tid, As[0], Bs[0]);
    for (int it = 0; it < nk; ++it) {
        const int cur = it & 1;
        __syncthreads();
        if (it + 1 < nk)
            stage64(Ab, lda, arow, Bb, ldb, (it + 1) << 6, tid, As[1 - cur], Bs[1 - cur]);
        compute64(As[cur], Bs[cur], wy, wx, quad, mrow, acc);
    }

    u16* Cb = C + rbase * ldc + (long)blockIdx.x * 128;
    const float* biasb = bias + (long)e * sBiasE + blockIdx.x * 128;
    #pragma unroll
    for (int ni = 0; ni < 4; ni++) {
        const int col = wx * 64 + ni * 16 + mrow;
        float bv = biasb[col];
        #pragma unroll
        for (int mi = 0; mi < 4; mi++) {
            #pragma unroll
            for (int r = 0; r < 4; r++) {
                const int row = wy * 64 + mi * 16 + quad * 4 + r;
                float v = acc[mi][ni][r] + bv;
                if (RELU) v = fmaxf(v, 0.f);
                Cb[(long)row * ldc + col] = f2bf_bits(v);
            }
        }
    }
}

// ---------------- FFN2 K-split: z=0 keys [0,1024), z=1 [1024,2048); f32 partials, no bias ----------------
// grid (4, 96, 2)
__global__ __launch_bounds__(256)
void gemm_ffn2_half_kernel(const u16* __restrict__ MID, const u16* __restrict__ W2T,
                           float* __restrict__ P0, float* __restrict__ P1,
                           const int* __restrict__ tmap, const int* __restrict__ tt) {
    const int b = blockIdx.y / 24, tile = blockIdx.y % 24;
    if (tile >= tt[b]) return;
    const int e = tmap[b * 32 + tile];
    __shared__ __align__(16) u16 As[2][128 * 64];
    __shared__ __align__(16) u16 Bs[2][128 * 64];
    const long rbase = (long)b * 3072 + tile * 128;
    const int koff = blockIdx.z * 1024;
    const u16* Ab = MID + rbase * 2048 + koff;
    const u16* Bb = W2T + (long)e * 1048576 + (long)blockIdx.x * 128 * 2048 + koff;

    const int tid = threadIdx.x;
    const int w = tid >> 6, lane = tid & 63;
    const int wy = w >> 1, wx = w & 1;
    const int quad = lane >> 4, mrow = lane & 15;

    long arow[4];
    #pragma unroll
    for (int j = 0; j < 4; ++j) arow[j] = (j * 256 + tid) >> 3;

    floatx4 acc[4][4];
    #pragma unroll
    for (int i = 0; i < 4; i++)
        #pragma unroll
        for (int j = 0; j < 4; j++)
            acc[i][j] = floatx4{0.f, 0.f, 0.f, 0.f};

    stage64(Ab, 2048, arow, Bb, 2048, 0, tid, As[0], Bs[0]);
    for (int it = 0; it < 16; ++it) {
        const int cur = it & 1;
        __syncthreads();
        if (it + 1 < 16)
            stage64(Ab, 2048, arow, Bb, 2048, (it + 1) << 6, tid, As[1 - cur], Bs[1 - cur]);
        compute64(As[cur], Bs[cur], wy, wx, quad, mrow, acc);
    }

    float* Cb = (blockIdx.z ? P1 : P0) + rbase * 512 + (long)blockIdx.x * 128;
    #pragma unroll
    for (int ni = 0; ni < 4; ni++) {
        const int col = wx * 64 + ni * 16 + mrow;
        #pragma unroll
        for (int mi = 0; mi < 4; mi++) {
            #pragma unroll
            for (int r = 0; r < 4; r++) {
                const int row = wy * 64 + mi * 16 + quad * 4 + r;
                Cb[(long)row * 512 + col] = acc[mi][ni][r];
            }
        }
    }
}

// ---------------- LN1 on packed rows ----------------
__global__ __launch_bounds__(128)
void ln1_kernel(const float* __restrict__ x, const u16* __restrict__ tc,
                const int* __restrict__ prix, const int* __restrict__ act,
                const int* __restrict__ tmap, const int* __restrict__ pt,
                const float* __restrict__ s_all, const float* __restrict__ b_all,
                u16* __restrict__ hb) {
    int blk = blockIdx.x;
    int b = blk / 3072, pslot = blk % 3072;
    if (pslot >= pt[b]) return;
    long row = (long)b * 3072 + pslot;
    int tid = threadIdx.x, w = tid >> 6, lane = tid & 63;
    if (!act[row]) {
        *(ushort4*)(hb + row * 512 + tid * 4) = make_ushort4(0, 0, 0, 0);
        return;
    }
    int r = prix[row];
    int e = tmap[b * 32 + (pslot >> 7)];
    float4 xv = *(const float4*)(x + (long)r * 512 + tid * 4);
    ushort4 tu = *(const ushort4*)(tc + row * 512 + tid * 4);
    float v[4] = {xv.x + bf_bits2f(tu.x), xv.y + bf_bits2f(tu.y),
                  xv.z + bf_bits2f(tu.z), xv.w + bf_bits2f(tu.w)};
    float sum = v[0] + v[1] + v[2] + v[3];
    #pragma unroll
    for (int o = 32; o; o >>= 1) sum += __shfl_down(sum, o, 64);
    __shared__ float sh[4];
    if (lane == 0) sh[w] = sum;
    __syncthreads();
    float mu = (sh[0] + sh[1]) * (1.f / 512.f);
    float sq = 0.f;
    #pragma unroll
    for (int j = 0; j < 4; j++) { float d = v[j] - mu; sq += d * d; }
    #pragma unroll
    for (int o = 32; o; o >>= 1) sq += __shfl_down(sq, o, 64);
    if (lane == 0) sh[2 + w] = sq;
    __syncthreads();
    float inv = 1.f / sqrtf((sh[2] + sh[3]) * (1.f / 512.f) + 1e-5f);
    float4 sv = *(const float4*)(s_all + e * 512 + tid * 4);
    float4 bv = *(const float4*)(b_all + e * 512 + tid * 4);
    ushort4 ub;
    ub.x = f2bf_bits((v[0] - mu) * inv * sv.x + bv.x);
    ub.y = f2bf_bits((v[1] - mu) * inv * sv.y + bv.y);
    ub.z = f2bf_bits((v[2] - mu) * inv * sv.z + bv.z);
    ub.w = f2bf_bits((v[3] - mu) * inv * sv.w + bv.w);
    *(ushort4*)(hb + row * 512 + tid * 4) = ub;
}

// ---------------- LN2 + FFN2 partial-sum + bias + weighted accumulate over all 8 experts ----------------
__global__ __launch_bounds__(128)
void ln2acc_kernel(const u16* __restrict__ hb, const float* __restrict__ p0,
                   const float* __restrict__ p1, const float* __restrict__ b2,
                   const float* __restrict__ s_all, const float* __restrict__ b_all,
                   const float* __restrict__ rw, const int* __restrict__ smap,
                   float* __restrict__ out) {
    long r = blockIdx.x;
    int b = (int)(r >> 10);
    int tid = threadIdx.x, w = tid >> 6, lane = tid & 63;
    __shared__ float sh[4];
    float4 acc = make_float4(0.f, 0.f, 0.f, 0.f);
    for (int e = 0; e < 8; e++) {
        int ps = smap[r * 8 + e];
        if (ps >= 0) {   // block-uniform
            float wgt = rw[r * 8 + e];
            long row = (long)b * 3072 + ps;
            ushort4 hu = *(const ushort4*)(hb + row * 512 + tid * 4);
            float4 f0 = *(const float4*)(p0 + row * 512 + tid * 4);
            float4 f1 = *(const float4*)(p1 + row * 512 + tid * 4);
            float4 bb = *(const float4*)(b2 + (long)e * 512 + tid * 4);
            float v[4] = {bf_bits2f(hu.x) + f0.x + f1.x + bb.x,
                          bf_bits2f(hu.y) + f0.y + f1.y + bb.y,
                          bf_bits2f(hu.z) + f0.z + f1.z + bb.z,
                          bf_bits2f(hu.w) + f0.w + f1.w + bb.w};
            float sum = v[0] + v[1] + v[2] + v[3];
            #pragma unroll
            for (int o = 32; o; o >>= 1) sum += __shfl_down(sum, o, 64);
            if (lane == 0) sh[w] = sum;
            __syncthreads();
            float mu = (sh[0] + sh[1]) * (1.f / 512.f);
            float sq = 0.f;
            #pragma unroll
            for (int j = 0; j < 4; j++) { float d = v[j] - mu; sq += d * d; }
            #pragma unroll
            for (int o = 32; o; o >>= 1) sq += __shfl_down(sq, o, 64);
            if (lane == 0) sh[2 + w] = sq;
            __syncthreads();
            float inv = 1.f / sqrtf((sh[2] + sh[3]) * (1.f / 512.f) + 1e-5f);
            float4 sv = *(const float4*)(s_all + e * 512 + tid * 4);
            float4 bv = *(const float4*)(b_all + e * 512 + tid * 4);
            acc.x += wgt * ((v[0] - mu) * inv * sv.x + bv.x);
            acc.y += wgt * ((v[1] - mu) * inv * sv.y + bv.y);
            acc.z += wgt * ((v[2] - mu) * inv * sv.z + bv.z);
            acc.w += wgt * ((v[3] - mu) * inv * sv.w + bv.w);
            __syncthreads();
        }
    }
    *(float4*)(out + r * 512 + tid * 4) = acc;
}

// ---------------- workspace layout (bytes), ws_size = 256 MiB ----------------
static const size_t WB_B   = 0;           // 48 MiB: wq,wk,wv,wo (8x262144 each), w1 (8x1048576), w2 (8x1048576)
static const size_t RW_B   = 50331648;    // f32 [4096][8]
static const size_t PB_B   = 50462720;    // f32 [3][8][512]
static const size_t TT_B   = 50511872;    // i32[4] tiles per b
static const size_t PT_B   = 50511888;    // i32[4] packed rows per b
static const size_t TMAP_B = 50511904;    // i32 [4][32]
static const size_t PRIX_B = 50512416;    // i32 [4][3072]
static const size_t ACT_B  = 50561568;    // i32 [4][3072]
static const size_t SMAP_B = 50610720;    // i32 [4096][8]
static const size_t XB_B   = 50741792;    // bf16 [4096][512]
static const size_t Q8_B   = 54936096;    // bf16 packed Q [4][3072][512] (12.6 MiB)
static const size_t K8_B   = 88490528;    // bf16 [8][4096][512] (32 MiB)
static const size_t VT_B   = 122044960;   // bf16 [8][16][128][1024] (32 MiB)
static const size_t S_B    = 155599392;   // scratch: FFN mid bf16 [4][3072][2048] (50.3 MiB)
static const size_t OC_B   = Q8_B;        // fused attn out: block-exclusive alias of QP
static const size_t TC_B   = K8_B;        // bf16 [4][3072][512] — K dead after attn
static const size_t HB_B   = Q8_B;        // LN1 out — OC dead after Wo
static const size_t MID_B  = S_B;         // ends at 205,931,040
static const size_t FP0_B  = VT_B;        // f32 [4][3072][512] = 25.2 MiB — VT dead after attn
static const size_t FP1_B  = 205931040;   // f32 [4][3072][512], ends 231,096,864 < 268,435,456

extern "C" void kernel_launch(void* const* d_in, const int* in_sizes, int n_in,
                              void* d_out, int out_size, void* d_ws, size_t ws_size,
                              hipStream_t stream) {
    const float* x      = (const float*)d_in[0];
    const float* gate_w = (const float*)d_in[1];
    const float* gate_b = (const float*)d_in[2];
    const float* ln1_s  = (const float*)d_in[3];
    const float* ln1_b  = (const float*)d_in[4];
    const float* ln2_s  = (const float*)d_in[5];
    const float* ln2_b  = (const float*)d_in[6];
    const float* wq = (const float*)d_in[7];
    const float* wk = (const float*)d_in[8];
    const float* wv = (const float*)d_in[9];
    const float* wo = (const float*)d_in[10];
    const float* bo = (const float*)d_in[14];
    const float* w1 = (const float*)d_in[15];
    const float* b1 = (const float*)d_in[16];
    const float* w2 = (const float*)d_in[17];
    const float* b2 = (const float*)d_in[18];
    float* out = (float*)d_out;

    char* ws = (char*)d_ws;
    u16*   WB   = (u16*)(ws + WB_B);
    float* RW   = (float*)(ws + RW_B);
    float* PB   = (float*)(ws + PB_B);
    int*   TT   = (int*)(ws + TT_B);
    int*   PT   = (int*)(ws + PT_B);
    int*   TMAP = (int*)(ws + TMAP_B);
    int*   PRIX = (int*)(ws + PRIX_B);
    int*   ACT  = (int*)(ws + ACT_B);
    int*   SMAP = (int*)(ws + SMAP_B);
    u16*   XB   = (u16*)(ws + XB_B);
    u16*   QP   = (u16*)(ws + Q8_B);
    u16*   K8   = (u16*)(ws + K8_B);
    u16*   VT8  = (u16*)(ws + VT_B);
    u16*   OC   = (u16*)(ws + OC_B);
    u16*   TC   = (u16*)(ws + TC_B);
    u16*   HB   = (u16*)(ws + HB_B);
    u16*   MID  = (u16*)(ws + MID_B);
    float* FP0  = (float*)(ws + FP0_B);
    float* FP1  = (float*)(ws + FP1_B);

    // ---- setup ----
    transpose_all_kernel<<<dim3(24576), dim3(32,8), 0, stream>>>(wq, wk, wv, wo, w1, w2, WB);
    // router + x-cast + bias-pack in one launch
    router_cast_kernel<<<4120, 512, 0, stream>>>(x, gate_w, gate_b, RW, out + 2097152, XB,
                                                 (const float*)d_in[11], (const float*)d_in[12],
                                                 (const float*)d_in[13], PB);
    build_lists_kernel<<<4, 256, 0, stream>>>(RW, PRIX, ACT, SMAP, TMAP, TT, PT);

    const float isq = 0.08838834764831845f;  // 1/sqrt(128)

    // ---- K + V for all 8 experts in one launch (z<8: K normal, z>=8: V transposed) ----
    gemm_kv_kernel<<<dim3(4,32,16), 256, 0, stream>>>(XB, WB + 2097152, K8, VT8, PB + 4096);
    // ---- Q only for packed (routed) rows, gathered from x (separate launch: 88-VGPR kv kernel) ----
    gemm_qp_kernel<<<dim3(4,96), 256, 0, stream>>>(XB, WB, QP, PB, TMAP, TT, PRIX);

    // ---- fused attention (R2-proven structure, 8 x 128-key steps) ----
    attn_fused_kernel<<<dim3(24, 16), 256, 0, stream>>>(QP, K8, VT8, OC, TMAP, TT, isq);

    // ---- Wo ----
    gemm_packed_kernel<false><<<dim3(4,96), 256, 0, stream>>>(
        OC, 512, WB + 6291456, 512, 262144, TC, 512, bo, 512, TMAP, TT, 512);
    // ---- LN1 ----
    ln1_kernel<<<12288, 128, 0, stream>>>(x, TC, PRIX, ACT, TMAP, PT, ln1_s, ln1_b, HB);
    // ---- FFN1 ----
    gemm_packed_kernel<true><<<dim3(16,96), 256, 0, stream>>>(
        HB, 512, WB + 8388608, 512, 1048576, MID, 2048, b1, 2048, TMAP, TT, 512);
    // ---- FFN2, K-split halves into f32 partials (2x occupancy) ----
    gemm_ffn2_half_kernel<<<dim3(4,96,2), 256, 0, stream>>>(
        MID, WB + 16777216, FP0, FP1, TMAP, TT);
    // ---- LN2 + partial-sum + bias + routing-weighted accumulate ----
    ln2acc_kernel<<<4096, 128, 0, stream>>>(HB, FP0, FP1, b2, ln2_s, ln2_b, RW, SMAP, out);
}